// Round 1
// baseline (1044.148 us; speedup 1.0000x reference)
//
#include <hip/hip_runtime.h>

#define BB 2
#define NN 8192
#define KK 16
#define SLICES 4
#define SLICE_LEN (NN / SLICES)   // 2048
#define QPB 64                    // queries per block (knn)

// ---------------------------------------------------------------- prep
// pts4[b*N+n] = (x,y,z, x^2+y^2+z^2); transpose att_w2 -> w2t(128,64);
// transpose mlp3_w2 -> w3bt(128,12)
__global__ __launch_bounds__(256) void prep_kernel(
    const float* __restrict__ x, float4* __restrict__ pts4,
    const float* __restrict__ aw2, float* __restrict__ w2t,
    const float* __restrict__ m3w2, float* __restrict__ w3bt)
{
    int t = blockIdx.x * 256 + threadIdx.x;
    if (t < BB * NN) {
        int b = t >> 13, n = t & (NN - 1);
        float x0 = x[(b * 3 + 0) * NN + n];
        float x1 = x[(b * 3 + 1) * NN + n];
        float x2 = x[(b * 3 + 2) * NN + n];
        // same fmaf chain as the knn dot so that d(self) == 0 bit-exactly
        float sq = fmaf(x2, x2, fmaf(x1, x1, __fmul_rn(x0, x0)));
        pts4[t] = make_float4(x0, x1, x2, sq);
    }
    if (t < 128 * 64) {           // w2t[r*64+o] = aw2[o*128+r]
        int r = t >> 6, o = t & 63;
        w2t[t] = aw2[o * 128 + r];
    }
    if (t < 128 * 12) {           // w3bt[r*12+o] = m3w2[o*128+r]
        int r = t / 12, o = t - r * 12;
        w3bt[t] = m3w2[o * 128 + r];
    }
}

// ---------------------------------------------------------------- knn
// block: 256 thr = 4 waves; wave w scans candidate slice w for 64 queries.
// Per-thread sorted-16 (ascending, stable => ties keep lower index like
// lax.top_k). 4 partial lists merged through LDS by wave 0.
__global__ __launch_bounds__(256) void knn_kernel(
    const float4* __restrict__ pts4, int* __restrict__ iout)
{
    __shared__ float4 tile[SLICES][64];
    __shared__ float  lds_d[SLICES][QPB][KK];
    __shared__ int    lds_i[SLICES][QPB][KK];

    const int t    = threadIdx.x;
    const int wv   = t >> 6;       // slice
    const int lane = t & 63;       // query within block
    const int b    = blockIdx.y;
    const int q    = blockIdx.x * QPB + lane;

    const float4 qp = pts4[b * NN + q];

    float dist[KK];
    int   nidx[KK];
#pragma unroll
    for (int i = 0; i < KK; ++i) { dist[i] = 3.0e38f; nidx[i] = 0; }

    const int cbase = wv * SLICE_LEN;
    for (int it = 0; it < SLICE_LEN / 64; ++it) {
        __syncthreads();
        tile[wv][lane] = pts4[b * NN + cbase + it * 64 + lane];
        __syncthreads();
#pragma unroll 8
        for (int mm = 0; mm < 64; ++mm) {
            float4 c = tile[wv][mm];
            float dot = fmaf(qp.z, c.z, fmaf(qp.y, c.y, __fmul_rn(qp.x, c.x)));
            float d = __fadd_rn(__fsub_rn(qp.w, __fmul_rn(2.0f, dot)), c.w);
            if (d < dist[KK - 1]) {
                int midx = cbase + it * 64 + mm;
#pragma unroll
                for (int i = KK - 1; i > 0; --i) {
                    bool c1 = d < dist[i];
                    bool c2 = d < dist[i - 1];
                    float nd = c2 ? dist[i - 1] : d;
                    int   ni = c2 ? nidx[i - 1] : midx;
                    dist[i] = c1 ? nd : dist[i];
                    nidx[i] = c1 ? ni : nidx[i];
                }
                if (d < dist[0]) { dist[0] = d; nidx[0] = midx; }
            }
        }
    }

    __syncthreads();
#pragma unroll
    for (int i = 0; i < KK; ++i) {
        lds_d[wv][lane][i] = dist[i];
        lds_i[wv][lane][i] = nidx[i];
    }
    __syncthreads();

    if (t < QPB) {
        int k0 = 0, k1 = 0, k2 = 0, k3 = 0;
        float h0 = lds_d[0][t][0], h1 = lds_d[1][t][0];
        float h2 = lds_d[2][t][0], h3 = lds_d[3][t][0];
        int* op = iout + ((size_t)b * NN + blockIdx.x * QPB + t) * KK;
        for (int k = 0; k < KK; ++k) {
            float best = h0; int bs = 0;
            if (h1 < best) { best = h1; bs = 1; }
            if (h2 < best) { best = h2; bs = 2; }
            if (h3 < best) { best = h3; bs = 3; }
            int sel;
            if (bs == 0) { sel = lds_i[0][t][k0]; ++k0; h0 = (k0 < KK) ? lds_d[0][t][k0] : 3.0e38f; }
            else if (bs == 1) { sel = lds_i[1][t][k1]; ++k1; h1 = (k1 < KK) ? lds_d[1][t][k1] : 3.0e38f; }
            else if (bs == 2) { sel = lds_i[2][t][k2]; ++k2; h2 = (k2 < KK) ? lds_d[2][t][k2] : 3.0e38f; }
            else               { sel = lds_i[3][t][k3]; ++k3; h3 = (k3 < KK) ? lds_d[3][t][k3] : 3.0e38f; }
            op[k] = sel;
        }
    }
}

// ---------------------------------------------------------------- f1
// f1[P][64] = relu(W2 * relu(W1 * x + b1) + b2), thread per point
__global__ __launch_bounds__(128) void f1_kernel(
    const float* __restrict__ x,
    const float* __restrict__ w1, const float* __restrict__ b1,
    const float* __restrict__ w2, const float* __restrict__ b2,
    float* __restrict__ f1)
{
    int P = blockIdx.x * 128 + threadIdx.x;
    if (P >= BB * NN) return;
    int b = P >> 13, n = P & (NN - 1);
    float x0 = x[(b * 3 + 0) * NN + n];
    float x1 = x[(b * 3 + 1) * NN + n];
    float x2 = x[(b * 3 + 2) * NN + n];
    float h[32];
#pragma unroll
    for (int o = 0; o < 32; ++o) {
        float v = fmaf(w1[o * 3 + 2], x2, fmaf(w1[o * 3 + 1], x1, fmaf(w1[o * 3 + 0], x0, b1[o])));
        h[o] = fmaxf(v, 0.f);
    }
    float4* out4 = (float4*)(f1 + (size_t)P * 64);
#pragma unroll
    for (int o4 = 0; o4 < 16; ++o4) {
        float vv[4];
#pragma unroll
        for (int u = 0; u < 4; ++u) {
            int o = o4 * 4 + u;
            float v = b2[o];
#pragma unroll
            for (int k = 0; k < 32; ++k) v = fmaf(w2[o * 32 + k], h[k], v);
            vv[u] = fmaxf(v, 0.f);
        }
        out4[o4] = make_float4(vv[0], vv[1], vv[2], vv[3]);
    }
}

// ---------------------------------------------------------------- attention
// lane = (point p in 0..3, neighbor j in 0..15; j==15 idle), wave = 4 points
__global__ __launch_bounds__(256, 2) void attn_kernel(
    const float* __restrict__ f1, const int* __restrict__ idx,
    const float* __restrict__ w1, const float* __restrict__ b1,
    const float* __restrict__ w2t, const float* __restrict__ b2,
    float* __restrict__ fagg)
{
    const int t = threadIdx.x;
    const int wv = t >> 6, lane = t & 63;
    const int p = lane >> 4, j = lane & 15;
    const int P = blockIdx.x * 16 + wv * 4 + p;   // < 16384
    const int b = P >> 13;
    const int jj = (j < 15) ? j : 14;
    const int nb = idx[(size_t)P * KK + 1 + jj];

    const float4* fnb = (const float4*)(f1 + ((size_t)b * NN + nb) * 64);
    const float4* fct = (const float4*)(f1 + (size_t)P * 64);
    float fk[64];
#pragma unroll
    for (int o4 = 0; o4 < 16; ++o4) {
        float4 A = fnb[o4], C = fct[o4];
        fk[o4 * 4 + 0] = A.x - C.x;
        fk[o4 * 4 + 1] = A.y - C.y;
        fk[o4 * 4 + 2] = A.z - C.z;
        fk[o4 * 4 + 3] = A.w - C.w;
    }

    float L[64];
#pragma unroll
    for (int o = 0; o < 64; ++o) L[o] = b2[o];

    for (int r = 0; r < 128; ++r) {
        const float4* wr4 = (const float4*)(w1 + (size_t)r * 64);
        float s0 = 0.f, s1 = 0.f, s2 = 0.f, s3 = 0.f;
#pragma unroll
        for (int k4 = 0; k4 < 16; ++k4) {
            float4 wvv = wr4[k4];
            s0 = fmaf(wvv.x, fk[k4 * 4 + 0], s0);
            s1 = fmaf(wvv.y, fk[k4 * 4 + 1], s1);
            s2 = fmaf(wvv.z, fk[k4 * 4 + 2], s2);
            s3 = fmaf(wvv.w, fk[k4 * 4 + 3], s3);
        }
        float h = fmaxf(b1[r] + ((s0 + s1) + (s2 + s3)), 0.f);
        const float4* w2r4 = (const float4*)(w2t + (size_t)r * 64);
#pragma unroll
        for (int o4 = 0; o4 < 16; ++o4) {
            float4 wvv = w2r4[o4];
            L[o4 * 4 + 0] = fmaf(wvv.x, h, L[o4 * 4 + 0]);
            L[o4 * 4 + 1] = fmaf(wvv.y, h, L[o4 * 4 + 1]);
            L[o4 * 4 + 2] = fmaf(wvv.z, h, L[o4 * 4 + 2]);
            L[o4 * 4 + 3] = fmaf(wvv.w, h, L[o4 * 4 + 3]);
        }
    }

    const bool act = (j < 15);
    float* outp = fagg + (size_t)P * 64;
    for (int o = 0; o < 64; ++o) {
        float l = act ? L[o] : -3.0e38f;
        l = fmaxf(l, __shfl_xor(l, 1));
        l = fmaxf(l, __shfl_xor(l, 2));
        l = fmaxf(l, __shfl_xor(l, 4));
        l = fmaxf(l, __shfl_xor(l, 8));
        float e = act ? __expf(L[o] - l) : 0.f;
        float s = e;
        s += __shfl_xor(s, 1); s += __shfl_xor(s, 2);
        s += __shfl_xor(s, 4); s += __shfl_xor(s, 8);
        float c = (e / s) * fk[o];
        c += __shfl_xor(c, 1); c += __shfl_xor(c, 2);
        c += __shfl_xor(c, 4); c += __shfl_xor(c, 8);
        if (j == (o & 15)) outp[o] = c;
    }
}

// ---------------------------------------------------------------- cov + mlp2
__global__ __launch_bounds__(128) void cov_kernel(
    const float4* __restrict__ pts4, const int* __restrict__ idx,
    const float* __restrict__ w, const float* __restrict__ bb,
    float* __restrict__ fcov)
{
    int P = blockIdx.x * 128 + threadIdx.x;
    if (P >= BB * NN) return;
    int b = P >> 13;
    const int4* ip4 = (const int4*)(idx + (size_t)P * KK);
    int ids[KK];
#pragma unroll
    for (int g = 0; g < 4; ++g) {
        int4 v = ip4[g];
        ids[g * 4 + 0] = v.x; ids[g * 4 + 1] = v.y;
        ids[g * 4 + 2] = v.z; ids[g * 4 + 3] = v.w;
    }
    float px[KK], py[KK], pz[KK];
#pragma unroll
    for (int k = 0; k < KK; ++k) {
        float4 c = pts4[b * NN + ids[k]];
        px[k] = c.x; py[k] = c.y; pz[k] = c.z;
    }
    float mx = 0.f, my = 0.f, mz = 0.f;
#pragma unroll
    for (int k = 0; k < KK; ++k) { mx += px[k]; my += py[k]; mz += pz[k]; }
    mx *= (1.f / 16.f); my *= (1.f / 16.f); mz *= (1.f / 16.f);
    float c00 = 0, c01 = 0, c02 = 0, c11 = 0, c12 = 0, c22 = 0;
#pragma unroll
    for (int k = 0; k < KK; ++k) {
        float dx = px[k] - mx, dy = py[k] - my, dz = pz[k] - mz;
        c00 = fmaf(dx, dx, c00); c01 = fmaf(dx, dy, c01); c02 = fmaf(dx, dz, c02);
        c11 = fmaf(dy, dy, c11); c12 = fmaf(dy, dz, c12); c22 = fmaf(dz, dz, c22);
    }
    const float inv = 1.f / 16.f;
    float cf[9] = { c00 * inv, c01 * inv, c02 * inv,
                    c01 * inv, c11 * inv, c12 * inv,
                    c02 * inv, c12 * inv, c22 * inv };
    float* out = fcov + (size_t)P * 32;
#pragma unroll
    for (int o = 0; o < 32; ++o) {
        float v = bb[o];
#pragma unroll
        for (int m = 0; m < 9; ++m) v = fmaf(w[o * 9 + m], cf[m], v);
        out[o] = fmaxf(v, 0.f);
    }
}

// ---------------------------------------------------------------- mlp3 + output
__global__ __launch_bounds__(128, 2) void mlp3_kernel(
    const float* __restrict__ fagg, const float* __restrict__ fcov,
    const float* __restrict__ w1, const float* __restrict__ b1,
    const float* __restrict__ w2t, const float* __restrict__ b2,
    const float* __restrict__ x, float* __restrict__ out)
{
    int P = blockIdx.x * 128 + threadIdx.x;
    if (P >= BB * NN) return;
    int b = P >> 13, n = P & (NN - 1);
    float f[96];
    const float4* fa4 = (const float4*)(fagg + (size_t)P * 64);
#pragma unroll
    for (int g = 0; g < 16; ++g) {
        float4 v = fa4[g];
        f[g * 4 + 0] = v.x; f[g * 4 + 1] = v.y; f[g * 4 + 2] = v.z; f[g * 4 + 3] = v.w;
    }
    const float4* fc4 = (const float4*)(fcov + (size_t)P * 32);
#pragma unroll
    for (int g = 0; g < 8; ++g) {
        float4 v = fc4[g];
        f[64 + g * 4 + 0] = v.x; f[64 + g * 4 + 1] = v.y;
        f[64 + g * 4 + 2] = v.z; f[64 + g * 4 + 3] = v.w;
    }
    float acc[12];
#pragma unroll
    for (int o = 0; o < 12; ++o) acc[o] = b2[o];
    for (int r = 0; r < 128; ++r) {
        const float4* wr4 = (const float4*)(w1 + (size_t)r * 96);
        float s0 = 0.f, s1 = 0.f, s2 = 0.f, s3 = 0.f;
#pragma unroll
        for (int k4 = 0; k4 < 24; ++k4) {
            float4 wv = wr4[k4];
            s0 = fmaf(wv.x, f[k4 * 4 + 0], s0);
            s1 = fmaf(wv.y, f[k4 * 4 + 1], s1);
            s2 = fmaf(wv.z, f[k4 * 4 + 2], s2);
            s3 = fmaf(wv.w, f[k4 * 4 + 3], s3);
        }
        float h = fmaxf(b1[r] + ((s0 + s1) + (s2 + s3)), 0.f);
        const float4* w2r4 = (const float4*)(w2t + (size_t)r * 12);
#pragma unroll
        for (int g = 0; g < 3; ++g) {
            float4 wv = w2r4[g];
            acc[g * 4 + 0] = fmaf(wv.x, h, acc[g * 4 + 0]);
            acc[g * 4 + 1] = fmaf(wv.y, h, acc[g * 4 + 1]);
            acc[g * 4 + 2] = fmaf(wv.z, h, acc[g * 4 + 2]);
            acc[g * 4 + 3] = fmaf(wv.w, h, acc[g * 4 + 3]);
        }
    }
#pragma unroll
    for (int i = 0; i < 12; ++i) {
        int c = i >> 2, rr = i & 3;
        float xv = x[((size_t)b * 3 + c) * NN + n];
        out[(((size_t)b * 3 + c) * 4 + rr) * NN + n] = xv + 0.15f * acc[i];
    }
}

// ---------------------------------------------------------------- launch
extern "C" void kernel_launch(void* const* d_in, const int* in_sizes, int n_in,
                              void* d_out, int out_size, void* d_ws, size_t ws_size,
                              hipStream_t stream)
{
    (void)in_sizes; (void)n_in; (void)out_size; (void)ws_size;
    const float* x    = (const float*)d_in[0];
    const float* m1w1 = (const float*)d_in[1];
    const float* m1b1 = (const float*)d_in[2];
    const float* m1w2 = (const float*)d_in[3];
    const float* m1b2 = (const float*)d_in[4];
    const float* m2w1 = (const float*)d_in[5];
    const float* m2b1 = (const float*)d_in[6];
    const float* m3w1 = (const float*)d_in[7];
    const float* m3b1 = (const float*)d_in[8];
    const float* m3w2 = (const float*)d_in[9];
    const float* m3b2 = (const float*)d_in[10];
    const float* aw1  = (const float*)d_in[11];
    const float* ab1  = (const float*)d_in[12];
    const float* aw2  = (const float*)d_in[13];
    const float* ab2  = (const float*)d_in[14];
    float* out = (float*)d_out;

    char* ws = (char*)d_ws;
    float4* pts4 = (float4*)(ws + 0);            //   262144 B
    int*    idxb = (int*)  (ws + 262144);        //  1048576 B
    float*  f1   = (float*)(ws + 1310720);       //  4194304 B
    float*  fagg = (float*)(ws + 5505024);       //  4194304 B
    float*  fcov = (float*)(ws + 9699328);       //  2097152 B
    float*  w2t  = (float*)(ws + 11796480);      //    32768 B
    float*  w3bt = (float*)(ws + 11829248);      //     6144 B

    prep_kernel<<<64, 256, 0, stream>>>(x, pts4, aw2, w2t, m3w2, w3bt);
    knn_kernel<<<dim3(NN / QPB, BB), 256, 0, stream>>>(pts4, idxb);
    f1_kernel<<<128, 128, 0, stream>>>(x, m1w1, m1b1, m1w2, m1b2, f1);
    attn_kernel<<<1024, 256, 0, stream>>>(f1, idxb, aw1, ab1, w2t, ab2, fagg);
    cov_kernel<<<128, 128, 0, stream>>>(pts4, idxb, m2w1, m2b1, fcov);
    mlp3_kernel<<<128, 128, 0, stream>>>(fagg, fcov, m3w1, m3b1, w3bt, m3b2, x, out);
}

// Round 2
// 775.870 us; speedup vs baseline: 1.3458x; 1.3458x over previous
//
#include <hip/hip_runtime.h>

#define BB 2
#define NN 8192
#define KK 16
#define SLICES 8
#define SLICE_LEN (NN / SLICES)   // 1024
#define QPB 64                    // queries per block (knn)
#define PENDCAP 16                // pending-buffer slots per thread (64 KB LDS)
typedef unsigned long long ull;
#define KINF 0xFFFFFFFFFFFFFFFFULL

// ---------------------------------------------------------------- prep
// pts4[b*N+n] = (x,y,z, x^2+y^2+z^2); transpose att_w2 -> w2t(128,64);
// transpose mlp3_w2 -> w3bt(128,12)
__global__ __launch_bounds__(256) void prep_kernel(
    const float* __restrict__ x, float4* __restrict__ pts4,
    const float* __restrict__ aw2, float* __restrict__ w2t,
    const float* __restrict__ m3w2, float* __restrict__ w3bt)
{
    int t = blockIdx.x * 256 + threadIdx.x;
    if (t < BB * NN) {
        int b = t >> 13, n = t & (NN - 1);
        float x0 = x[(b * 3 + 0) * NN + n];
        float x1 = x[(b * 3 + 1) * NN + n];
        float x2 = x[(b * 3 + 2) * NN + n];
        // same fmaf chain as the knn dot so that d(self) == 0 bit-exactly
        float sq = fmaf(x2, x2, fmaf(x1, x1, __fmul_rn(x0, x0)));
        pts4[t] = make_float4(x0, x1, x2, sq);
    }
    if (t < 128 * 64) {           // w2t[r*64+o] = aw2[o*128+r]
        int r = t >> 6, o = t & 63;
        w2t[t] = aw2[o * 128 + r];
    }
    if (t < 128 * 12) {           // w3bt[r*12+o] = m3w2[o*128+r]
        int r = t / 12, o = t - r * 12;
        w3bt[t] = m3w2[o * 128 + r];
    }
}

// ---------------------------------------------------------------- knn
// 512 thr = 8 waves; wave w = slice w (1024 candidates), all 64 lanes = 64
// queries scan the same candidate (wave-uniform scalar loads). Selection is
// deferred: candidates passing a stale threshold are pushed to an LDS
// pending buffer; the 96-inst sorted-insert runs only in drains (wave-any
// pend>=8, checked per 8 candidates). Keys = (monotone f32 bits << 32) | idx
// so ordering + index tie-break match lax.top_k exactly.
__global__ __launch_bounds__(512) void knn_kernel(
    const float4* __restrict__ pts4, int* __restrict__ iout)
{
    __shared__ ull smem[PENDCAP * 512];   // 64 KB; reused for the merge lists

    const int t    = threadIdx.x;
    const int wv   = t >> 6;
    const int lane = t & 63;
    const int b    = blockIdx.y;
    const int q    = blockIdx.x * QPB + lane;
    const int sl   = __builtin_amdgcn_readfirstlane(wv);

    const float4 qp = pts4[b * NN + q];
    const float4* __restrict__ cp = pts4 + (size_t)b * NN + (size_t)sl * SLICE_LEN;
    const unsigned cbase = sl * SLICE_LEN;

    ull list[KK];
#pragma unroll
    for (int i = 0; i < KK; ++i) list[i] = KINF;
    ull curmax = KINF;
    int pend = 0;

    for (int i0 = 0; i0 < SLICE_LEN; i0 += 8) {
#pragma unroll
        for (int u = 0; u < 8; ++u) {
            const int ci = i0 + u;
            float4 c = cp[ci];
            float dot = fmaf(qp.z, c.z, fmaf(qp.y, c.y, __fmul_rn(qp.x, c.x)));
            float d = __fadd_rn(__fsub_rn(qp.w, __fmul_rn(2.0f, dot)), c.w);
            unsigned ud = __float_as_uint(d);
            ud ^= ((unsigned)((int)ud >> 31)) | 0x80000000u;
            ull key = ((ull)ud << 32) | (unsigned)(cbase + ci);
            smem[(size_t)pend * 512 + t] = key;      // branchless push
            pend += (key < curmax) ? 1 : 0;
        }
        if (__any(pend >= 8)) {                       // drain (wave-uniform)
            for (int j = 0; j < PENDCAP - 1; ++j) {
                if (!__any(j < pend)) break;
                ull v = smem[(size_t)j * 512 + t];
                ull k = (j < pend) ? v : KINF;
#pragma unroll
                for (int i = KK - 1; i > 0; --i) {
                    bool c1 = k < list[i];
                    bool c2 = k < list[i - 1];
                    ull nd = c2 ? list[i - 1] : k;
                    list[i] = c1 ? nd : list[i];
                }
                list[0] = (k < list[0]) ? k : list[0];
            }
            pend = 0;
            curmax = list[KK - 1];
        }
    }
    // final drain
    for (int j = 0; j < PENDCAP - 1; ++j) {
        if (!__any(j < pend)) break;
        ull v = smem[(size_t)j * 512 + t];
        ull k = (j < pend) ? v : KINF;
#pragma unroll
        for (int i = KK - 1; i > 0; --i) {
            bool c1 = k < list[i];
            bool c2 = k < list[i - 1];
            ull nd = c2 ? list[i - 1] : k;
            list[i] = c1 ? nd : list[i];
        }
        list[0] = (k < list[0]) ? k : list[0];
    }

    __syncthreads();                                   // pend reads done
    // M(s,j,lane) = smem[(s*16+j)*64 + lane]
#pragma unroll
    for (int j = 0; j < KK; ++j) smem[(size_t)((wv * KK + j) * 64 + lane)] = list[j];
    __syncthreads();

    if (t < QPB) {                                     // 8-way merge, 1 thr/query
        ull h[SLICES];
        int kc[SLICES];
#pragma unroll
        for (int s = 0; s < SLICES; ++s) { h[s] = smem[(size_t)((s * KK) * 64 + t)]; kc[s] = 0; }
        int* op = iout + ((size_t)b * NN + (size_t)blockIdx.x * QPB + t) * KK;
        for (int o = 0; o < KK; ++o) {
            ull best = h[0]; int bs = 0;
#pragma unroll
            for (int s = 1; s < SLICES; ++s) { if (h[s] < best) { best = h[s]; bs = s; } }
            op[o] = (int)(unsigned)(best & 0xFFFFFFFFULL);
#pragma unroll
            for (int s = 0; s < SLICES; ++s) {
                bool adv = (s == bs);
                if (adv) {
                    kc[s]++;
                    h[s] = (kc[s] < KK) ? smem[(size_t)((s * KK + kc[s]) * 64 + t)] : KINF;
                }
            }
        }
    }
}

// ---------------------------------------------------------------- f1
// f1[P][64] = relu(W2 * relu(W1 * x + b1) + b2), thread per point
__global__ __launch_bounds__(128) void f1_kernel(
    const float* __restrict__ x,
    const float* __restrict__ w1, const float* __restrict__ b1,
    const float* __restrict__ w2, const float* __restrict__ b2,
    float* __restrict__ f1)
{
    int P = blockIdx.x * 128 + threadIdx.x;
    if (P >= BB * NN) return;
    int b = P >> 13, n = P & (NN - 1);
    float x0 = x[(b * 3 + 0) * NN + n];
    float x1 = x[(b * 3 + 1) * NN + n];
    float x2 = x[(b * 3 + 2) * NN + n];
    float h[32];
#pragma unroll
    for (int o = 0; o < 32; ++o) {
        float v = fmaf(w1[o * 3 + 2], x2, fmaf(w1[o * 3 + 1], x1, fmaf(w1[o * 3 + 0], x0, b1[o])));
        h[o] = fmaxf(v, 0.f);
    }
    float4* out4 = (float4*)(f1 + (size_t)P * 64);
#pragma unroll
    for (int o4 = 0; o4 < 16; ++o4) {
        float vv[4];
#pragma unroll
        for (int u = 0; u < 4; ++u) {
            int o = o4 * 4 + u;
            float v = b2[o];
#pragma unroll
            for (int k = 0; k < 32; ++k) v = fmaf(w2[o * 32 + k], h[k], v);
            vv[u] = fmaxf(v, 0.f);
        }
        out4[o4] = make_float4(vv[0], vv[1], vv[2], vv[3]);
    }
}

// ---------------------------------------------------------------- attention
// lane = (point p in 0..3, neighbor j in 0..15; j==15 idle), wave = 4 points
__global__ __launch_bounds__(256, 2) void attn_kernel(
    const float* __restrict__ f1, const int* __restrict__ idx,
    const float* __restrict__ w1, const float* __restrict__ b1,
    const float* __restrict__ w2t, const float* __restrict__ b2,
    float* __restrict__ fagg)
{
    const int t = threadIdx.x;
    const int wv = t >> 6, lane = t & 63;
    const int p = lane >> 4, j = lane & 15;
    const int P = blockIdx.x * 16 + wv * 4 + p;   // < 16384
    const int b = P >> 13;
    const int jj = (j < 15) ? j : 14;
    const int nb = idx[(size_t)P * KK + 1 + jj];

    const float4* fnb = (const float4*)(f1 + ((size_t)b * NN + nb) * 64);
    const float4* fct = (const float4*)(f1 + (size_t)P * 64);
    float fk[64];
#pragma unroll
    for (int o4 = 0; o4 < 16; ++o4) {
        float4 A = fnb[o4], C = fct[o4];
        fk[o4 * 4 + 0] = A.x - C.x;
        fk[o4 * 4 + 1] = A.y - C.y;
        fk[o4 * 4 + 2] = A.z - C.z;
        fk[o4 * 4 + 3] = A.w - C.w;
    }

    float L[64];
#pragma unroll
    for (int o = 0; o < 64; ++o) L[o] = b2[o];

    for (int r = 0; r < 128; ++r) {
        const float4* wr4 = (const float4*)(w1 + (size_t)r * 64);
        float s0 = 0.f, s1 = 0.f, s2 = 0.f, s3 = 0.f;
#pragma unroll
        for (int k4 = 0; k4 < 16; ++k4) {
            float4 wvv = wr4[k4];
            s0 = fmaf(wvv.x, fk[k4 * 4 + 0], s0);
            s1 = fmaf(wvv.y, fk[k4 * 4 + 1], s1);
            s2 = fmaf(wvv.z, fk[k4 * 4 + 2], s2);
            s3 = fmaf(wvv.w, fk[k4 * 4 + 3], s3);
        }
        float h = fmaxf(b1[r] + ((s0 + s1) + (s2 + s3)), 0.f);
        const float4* w2r4 = (const float4*)(w2t + (size_t)r * 64);
#pragma unroll
        for (int o4 = 0; o4 < 16; ++o4) {
            float4 wvv = w2r4[o4];
            L[o4 * 4 + 0] = fmaf(wvv.x, h, L[o4 * 4 + 0]);
            L[o4 * 4 + 1] = fmaf(wvv.y, h, L[o4 * 4 + 1]);
            L[o4 * 4 + 2] = fmaf(wvv.z, h, L[o4 * 4 + 2]);
            L[o4 * 4 + 3] = fmaf(wvv.w, h, L[o4 * 4 + 3]);
        }
    }

    const bool act = (j < 15);
    float* outp = fagg + (size_t)P * 64;
    for (int o = 0; o < 64; ++o) {
        float l = act ? L[o] : -3.0e38f;
        l = fmaxf(l, __shfl_xor(l, 1));
        l = fmaxf(l, __shfl_xor(l, 2));
        l = fmaxf(l, __shfl_xor(l, 4));
        l = fmaxf(l, __shfl_xor(l, 8));
        float e = act ? __expf(L[o] - l) : 0.f;
        float s = e;
        s += __shfl_xor(s, 1); s += __shfl_xor(s, 2);
        s += __shfl_xor(s, 4); s += __shfl_xor(s, 8);
        float c = (e / s) * fk[o];
        c += __shfl_xor(c, 1); c += __shfl_xor(c, 2);
        c += __shfl_xor(c, 4); c += __shfl_xor(c, 8);
        if (j == (o & 15)) outp[o] = c;
    }
}

// ---------------------------------------------------------------- cov + mlp2
__global__ __launch_bounds__(128) void cov_kernel(
    const float4* __restrict__ pts4, const int* __restrict__ idx,
    const float* __restrict__ w, const float* __restrict__ bb,
    float* __restrict__ fcov)
{
    int P = blockIdx.x * 128 + threadIdx.x;
    if (P >= BB * NN) return;
    int b = P >> 13;
    const int4* ip4 = (const int4*)(idx + (size_t)P * KK);
    int ids[KK];
#pragma unroll
    for (int g = 0; g < 4; ++g) {
        int4 v = ip4[g];
        ids[g * 4 + 0] = v.x; ids[g * 4 + 1] = v.y;
        ids[g * 4 + 2] = v.z; ids[g * 4 + 3] = v.w;
    }
    float px[KK], py[KK], pz[KK];
#pragma unroll
    for (int k = 0; k < KK; ++k) {
        float4 c = pts4[b * NN + ids[k]];
        px[k] = c.x; py[k] = c.y; pz[k] = c.z;
    }
    float mx = 0.f, my = 0.f, mz = 0.f;
#pragma unroll
    for (int k = 0; k < KK; ++k) { mx += px[k]; my += py[k]; mz += pz[k]; }
    mx *= (1.f / 16.f); my *= (1.f / 16.f); mz *= (1.f / 16.f);
    float c00 = 0, c01 = 0, c02 = 0, c11 = 0, c12 = 0, c22 = 0;
#pragma unroll
    for (int k = 0; k < KK; ++k) {
        float dx = px[k] - mx, dy = py[k] - my, dz = pz[k] - mz;
        c00 = fmaf(dx, dx, c00); c01 = fmaf(dx, dy, c01); c02 = fmaf(dx, dz, c02);
        c11 = fmaf(dy, dy, c11); c12 = fmaf(dy, dz, c12); c22 = fmaf(dz, dz, c22);
    }
    const float inv = 1.f / 16.f;
    float cf[9] = { c00 * inv, c01 * inv, c02 * inv,
                    c01 * inv, c11 * inv, c12 * inv,
                    c02 * inv, c12 * inv, c22 * inv };
    float* out = fcov + (size_t)P * 32;
#pragma unroll
    for (int o = 0; o < 32; ++o) {
        float v = bb[o];
#pragma unroll
        for (int m = 0; m < 9; ++m) v = fmaf(w[o * 9 + m], cf[m], v);
        out[o] = fmaxf(v, 0.f);
    }
}

// ---------------------------------------------------------------- mlp3 + output
__global__ __launch_bounds__(128, 2) void mlp3_kernel(
    const float* __restrict__ fagg, const float* __restrict__ fcov,
    const float* __restrict__ w1, const float* __restrict__ b1,
    const float* __restrict__ w2t, const float* __restrict__ b2,
    const float* __restrict__ x, float* __restrict__ out)
{
    int P = blockIdx.x * 128 + threadIdx.x;
    if (P >= BB * NN) return;
    int b = P >> 13, n = P & (NN - 1);
    float f[96];
    const float4* fa4 = (const float4*)(fagg + (size_t)P * 64);
#pragma unroll
    for (int g = 0; g < 16; ++g) {
        float4 v = fa4[g];
        f[g * 4 + 0] = v.x; f[g * 4 + 1] = v.y; f[g * 4 + 2] = v.z; f[g * 4 + 3] = v.w;
    }
    const float4* fc4 = (const float4*)(fcov + (size_t)P * 32);
#pragma unroll
    for (int g = 0; g < 8; ++g) {
        float4 v = fc4[g];
        f[64 + g * 4 + 0] = v.x; f[64 + g * 4 + 1] = v.y;
        f[64 + g * 4 + 2] = v.z; f[64 + g * 4 + 3] = v.w;
    }
    float acc[12];
#pragma unroll
    for (int o = 0; o < 12; ++o) acc[o] = b2[o];
    for (int r = 0; r < 128; ++r) {
        const float4* wr4 = (const float4*)(w1 + (size_t)r * 96);
        float s0 = 0.f, s1 = 0.f, s2 = 0.f, s3 = 0.f;
#pragma unroll
        for (int k4 = 0; k4 < 24; ++k4) {
            float4 wv = wr4[k4];
            s0 = fmaf(wv.x, f[k4 * 4 + 0], s0);
            s1 = fmaf(wv.y, f[k4 * 4 + 1], s1);
            s2 = fmaf(wv.z, f[k4 * 4 + 2], s2);
            s3 = fmaf(wv.w, f[k4 * 4 + 3], s3);
        }
        float h = fmaxf(b1[r] + ((s0 + s1) + (s2 + s3)), 0.f);
        const float4* w2r4 = (const float4*)(w2t + (size_t)r * 12);
#pragma unroll
        for (int g = 0; g < 3; ++g) {
            float4 wv = w2r4[g];
            acc[g * 4 + 0] = fmaf(wv.x, h, acc[g * 4 + 0]);
            acc[g * 4 + 1] = fmaf(wv.y, h, acc[g * 4 + 1]);
            acc[g * 4 + 2] = fmaf(wv.z, h, acc[g * 4 + 2]);
            acc[g * 4 + 3] = fmaf(wv.w, h, acc[g * 4 + 3]);
        }
    }
#pragma unroll
    for (int i = 0; i < 12; ++i) {
        int c = i >> 2, rr = i & 3;
        float xv = x[((size_t)b * 3 + c) * NN + n];
        out[(((size_t)b * 3 + c) * 4 + rr) * NN + n] = xv + 0.15f * acc[i];
    }
}

// ---------------------------------------------------------------- launch
extern "C" void kernel_launch(void* const* d_in, const int* in_sizes, int n_in,
                              void* d_out, int out_size, void* d_ws, size_t ws_size,
                              hipStream_t stream)
{
    (void)in_sizes; (void)n_in; (void)out_size; (void)ws_size;
    const float* x    = (const float*)d_in[0];
    const float* m1w1 = (const float*)d_in[1];
    const float* m1b1 = (const float*)d_in[2];
    const float* m1w2 = (const float*)d_in[3];
    const float* m1b2 = (const float*)d_in[4];
    const float* m2w1 = (const float*)d_in[5];
    const float* m2b1 = (const float*)d_in[6];
    const float* m3w1 = (const float*)d_in[7];
    const float* m3b1 = (const float*)d_in[8];
    const float* m3w2 = (const float*)d_in[9];
    const float* m3b2 = (const float*)d_in[10];
    const float* aw1  = (const float*)d_in[11];
    const float* ab1  = (const float*)d_in[12];
    const float* aw2  = (const float*)d_in[13];
    const float* ab2  = (const float*)d_in[14];
    float* out = (float*)d_out;

    char* ws = (char*)d_ws;
    float4* pts4 = (float4*)(ws + 0);            //   262144 B
    int*    idxb = (int*)  (ws + 262144);        //  1048576 B
    float*  f1   = (float*)(ws + 1310720);       //  4194304 B
    float*  fagg = (float*)(ws + 5505024);       //  4194304 B
    float*  fcov = (float*)(ws + 9699328);       //  2097152 B
    float*  w2t  = (float*)(ws + 11796480);      //    32768 B
    float*  w3bt = (float*)(ws + 11829248);      //     6144 B

    prep_kernel<<<64, 256, 0, stream>>>(x, pts4, aw2, w2t, m3w2, w3bt);
    knn_kernel<<<dim3(NN / QPB, BB), 512, 0, stream>>>(pts4, idxb);
    f1_kernel<<<128, 128, 0, stream>>>(x, m1w1, m1b1, m1w2, m1b2, f1);
    attn_kernel<<<1024, 256, 0, stream>>>(f1, idxb, aw1, ab1, w2t, ab2, fagg);
    cov_kernel<<<128, 128, 0, stream>>>(pts4, idxb, m2w1, m2b1, fcov);
    mlp3_kernel<<<128, 128, 0, stream>>>(fagg, fcov, m3w1, m3b1, w3bt, m3b2, x, out);
}

// Round 4
// 495.478 us; speedup vs baseline: 2.1074x; 1.5659x over previous
//
#include <hip/hip_runtime.h>

#define BB 2
#define NN 8192
#define KK 16
#define QPB 64
#define PENDCAP 16
#define PRE 256          // prefix candidates per slice (8 slices -> 2048 sample)
#define CAP 32           // buffered survivors per (query, slice)
typedef unsigned long long ull;
typedef unsigned short ushort;
#define KINF 0xFFFFFFFFFFFFFFFFULL

typedef __attribute__((ext_vector_type(8))) short short8;
typedef __attribute__((ext_vector_type(4))) float f32x4;

static __device__ __forceinline__ ushort f2bf(float f) {
    unsigned u = __float_as_uint(f);
    unsigned r = (u + 0x7FFFu + ((u >> 16) & 1u)) >> 16;
    return (ushort)r;
}
static __device__ __forceinline__ float bf2f(ushort s) {
    return __uint_as_float(((unsigned)s) << 16);
}

// ---------------------------------------------------------------- prep
__global__ __launch_bounds__(256) void prep_kernel(
    const float* __restrict__ x, float4* __restrict__ pts4,
    const float* __restrict__ m3w2, float* __restrict__ w3bt)
{
    int t = blockIdx.x * 256 + threadIdx.x;
    if (t < BB * NN) {
        int b = t >> 13, n = t & (NN - 1);
        float x0 = x[(b * 3 + 0) * NN + n];
        float x1 = x[(b * 3 + 1) * NN + n];
        float x2 = x[(b * 3 + 2) * NN + n];
        // same fmaf chain as the knn dot so that d(self) == 0 bit-exactly
        float sq = fmaf(x2, x2, fmaf(x1, x1, __fmul_rn(x0, x0)));
        pts4[t] = make_float4(x0, x1, x2, sq);
    }
    if (t < 128 * 12) {           // w3bt[r*12+o] = m3w2[o*128+r]
        int r = t / 12, o = t - r * 12;
        w3bt[t] = m3w2[o * 128 + r];
    }
}

// ---------------------------------------------------------------- knn K1: prefix -> per-query threshold
__global__ __launch_bounds__(512) void knn_prefix_kernel(
    const float4* __restrict__ pts4, ull* __restrict__ thrb)
{
    __shared__ ull smem[PENDCAP * 512];   // 64 KB

    const int t    = threadIdx.x;
    const int wv   = t >> 6;
    const int lane = t & 63;
    const int b    = blockIdx.y;
    const int q    = blockIdx.x * QPB + lane;
    const int sl   = __builtin_amdgcn_readfirstlane(wv);

    const float4 qp = pts4[b * NN + q];
    const float4* __restrict__ cp = pts4 + (size_t)b * NN + (size_t)sl * 1024;
    const unsigned cbase = sl * 1024;

    ull list[KK];
#pragma unroll
    for (int i = 0; i < KK; ++i) list[i] = KINF;
    ull curmax = KINF;
    int pend = 0;

    for (int i0 = 0; i0 < PRE; i0 += 8) {
#pragma unroll
        for (int u = 0; u < 8; ++u) {
            const int ci = i0 + u;
            float4 c = cp[ci];
            float dot = fmaf(qp.z, c.z, fmaf(qp.y, c.y, __fmul_rn(qp.x, c.x)));
            float d = __fadd_rn(__fsub_rn(qp.w, __fmul_rn(2.0f, dot)), c.w);
            unsigned ud = __float_as_uint(d);
            ud ^= ((unsigned)((int)ud >> 31)) | 0x80000000u;
            ull key = ((ull)ud << 32) | (unsigned)(cbase + ci);
            smem[(size_t)pend * 512 + t] = key;      // branchless push
            pend += (key < curmax) ? 1 : 0;
        }
        if (__any(pend >= 8)) {
            for (int j = 0; j < PENDCAP - 1; ++j) {
                if (!__any(j < pend)) break;
                ull v = smem[(size_t)j * 512 + t];
                ull k = (j < pend) ? v : KINF;
#pragma unroll
                for (int i = KK - 1; i > 0; --i) {
                    bool c1 = k < list[i];
                    bool c2 = k < list[i - 1];
                    ull nd = c2 ? list[i - 1] : k;
                    list[i] = c1 ? nd : list[i];
                }
                list[0] = (k < list[0]) ? k : list[0];
            }
            pend = 0;
            curmax = list[KK - 1];
        }
    }
    for (int j = 0; j < PENDCAP - 1; ++j) {
        if (!__any(j < pend)) break;
        ull v = smem[(size_t)j * 512 + t];
        ull k = (j < pend) ? v : KINF;
#pragma unroll
        for (int i = KK - 1; i > 0; --i) {
            bool c1 = k < list[i];
            bool c2 = k < list[i - 1];
            ull nd = c2 ? list[i - 1] : k;
            list[i] = c1 ? nd : list[i];
        }
        list[0] = (k < list[0]) ? k : list[0];
    }

    __syncthreads();
#pragma unroll
    for (int j = 0; j < KK; ++j) smem[(size_t)((wv * KK + j) * 64 + lane)] = list[j];
    __syncthreads();

    if (t < QPB) {
        ull h[8];
        int kc[8];
#pragma unroll
        for (int s = 0; s < 8; ++s) { h[s] = smem[(size_t)((s * KK) * 64 + t)]; kc[s] = 0; }
        ull best = KINF;
        for (int o = 0; o < KK; ++o) {
            best = h[0]; int bs = 0;
#pragma unroll
            for (int s = 1; s < 8; ++s) { if (h[s] < best) { best = h[s]; bs = s; } }
#pragma unroll
            for (int s = 0; s < 8; ++s) {
                if (s == bs) {
                    kc[s]++;
                    h[s] = (kc[s] < KK) ? smem[(size_t)((s * KK + kc[s]) * 64 + t)] : KINF;
                }
            }
        }
        thrb[(size_t)b * NN + blockIdx.x * QPB + t] = best;   // 16th smallest of prefix
    }
}

// ---------------------------------------------------------------- knn K2: full scan vs threshold
// Candidates passing thr are buffered (idx fits ushort). ~11 inst/cand.
__global__ __launch_bounds__(512) void knn_scan_kernel(
    const float4* __restrict__ pts4, const ull* __restrict__ thrb,
    ushort* __restrict__ buf, int* __restrict__ cnt)
{
    const int t    = threadIdx.x;
    const int wv   = t >> 6;
    const int lane = t & 63;
    const int b    = blockIdx.y;
    const int q    = blockIdx.x * QPB + lane;          // within batch
    const int sl   = __builtin_amdgcn_readfirstlane(wv);

    const float4 qp = pts4[b * NN + q];
    const ull thrk  = thrb[(size_t)b * NN + q];
    const float4* __restrict__ cp = pts4 + (size_t)b * NN + (size_t)sl * 1024;
    const unsigned cbase = sl * 1024;

    const int cell = (((int)(b * NN) + q) << 3) + sl;  // (global q)*8 + slice
    ushort* __restrict__ bp = buf + (size_t)cell * CAP;
    int pend = 0;

    for (int i0 = 0; i0 < 1024; i0 += 4) {
#pragma unroll
        for (int u = 0; u < 4; ++u) {
            const int ci = i0 + u;
            float4 c = cp[ci];
            float dot = fmaf(qp.z, c.z, fmaf(qp.y, c.y, __fmul_rn(qp.x, c.x)));
            float d = __fadd_rn(__fsub_rn(qp.w, __fmul_rn(2.0f, dot)), c.w);
            unsigned ud = __float_as_uint(d);
            ud ^= ((unsigned)((int)ud >> 31)) | 0x80000000u;
            ull key = ((ull)ud << 32) | (unsigned)(cbase + ci);
            if (key <= thrk) {
                if (pend < CAP) bp[pend] = (ushort)(cbase + ci);
                pend++;
            }
        }
    }
    cnt[cell] = (pend < CAP) ? pend : CAP;
}

// ---------------------------------------------------------------- knn K3: exact select of survivors
// 256 thr = 4 waves; wave = 16 queries x 4 lanes (2 slices each); recompute
// exact keys, sorted-insert, 4-way merge -> final idx. 64 queries per block.
__global__ __launch_bounds__(256) void knn_select_kernel(
    const float4* __restrict__ pts4, const ushort* __restrict__ buf,
    const int* __restrict__ cnt, int* __restrict__ iout)
{
    __shared__ ull sm3[4][4][16][KK];   // 32 KB

    const int t = threadIdx.x;
    const int wv = t >> 6, lane = t & 63;
    const int qq = lane & 15, hh = lane >> 4;
    const int q  = (blockIdx.x * 4 + wv) * 16 + qq;    // global query 0..16383
    const int b  = q >> 13;

    const float4 qp = pts4[q];
    ull list[KK];
#pragma unroll
    for (int i = 0; i < KK; ++i) list[i] = KINF;

#pragma unroll
    for (int ss = 0; ss < 2; ++ss) {
        const int s = hh * 2 + ss;
        const int cell = (q << 3) + s;
        const int n = cnt[cell];
        const ushort* bp = buf + (size_t)cell * CAP;
        for (int i = 0; i < n; ++i) {
            int id = bp[i];
            float4 c = pts4[b * NN + id];
            float dot = fmaf(qp.z, c.z, fmaf(qp.y, c.y, __fmul_rn(qp.x, c.x)));
            float d = __fadd_rn(__fsub_rn(qp.w, __fmul_rn(2.0f, dot)), c.w);
            unsigned ud = __float_as_uint(d);
            ud ^= ((unsigned)((int)ud >> 31)) | 0x80000000u;
            ull k = ((ull)ud << 32) | (unsigned)id;
#pragma unroll
            for (int i2 = KK - 1; i2 > 0; --i2) {
                bool c1 = k < list[i2];
                bool c2 = k < list[i2 - 1];
                ull nd = c2 ? list[i2 - 1] : k;
                list[i2] = c1 ? nd : list[i2];
            }
            list[0] = (k < list[0]) ? k : list[0];
        }
    }

#pragma unroll
    for (int k = 0; k < KK; ++k) sm3[wv][hh][qq][k] = list[k];

    if (hh == 0) {
        ull h[4]; int kc[4];
#pragma unroll
        for (int s = 0; s < 4; ++s) { h[s] = sm3[wv][s][qq][0]; kc[s] = 0; }
        int* op = iout + (size_t)q * KK;
        for (int o = 0; o < KK; ++o) {
            ull best = h[0]; int bs = 0;
#pragma unroll
            for (int s = 1; s < 4; ++s) { if (h[s] < best) { best = h[s]; bs = s; } }
            op[o] = (int)(unsigned)(best & 0xFFFFFFFFULL);
#pragma unroll
            for (int s = 0; s < 4; ++s) {
                if (s == bs) {
                    kc[s]++;
                    h[s] = (kc[s] < KK) ? sm3[wv][s][qq][kc[s]] : KINF;
                }
            }
        }
    }
}

// ---------------------------------------------------------------- f1
__global__ __launch_bounds__(128) void f1_kernel(
    const float* __restrict__ x,
    const float* __restrict__ w1, const float* __restrict__ b1,
    const float* __restrict__ w2, const float* __restrict__ b2,
    float* __restrict__ f1)
{
    int P = blockIdx.x * 128 + threadIdx.x;
    if (P >= BB * NN) return;
    int b = P >> 13, n = P & (NN - 1);
    float x0 = x[(b * 3 + 0) * NN + n];
    float x1 = x[(b * 3 + 1) * NN + n];
    float x2 = x[(b * 3 + 2) * NN + n];
    float h[32];
#pragma unroll
    for (int o = 0; o < 32; ++o) {
        float v = fmaf(w1[o * 3 + 2], x2, fmaf(w1[o * 3 + 1], x1, fmaf(w1[o * 3 + 0], x0, b1[o])));
        h[o] = fmaxf(v, 0.f);
    }
    float4* out4 = (float4*)(f1 + (size_t)P * 64);
#pragma unroll
    for (int o4 = 0; o4 < 16; ++o4) {
        float vv[4];
#pragma unroll
        for (int u = 0; u < 4; ++u) {
            int o = o4 * 4 + u;
            float v = b2[o];
#pragma unroll
            for (int k = 0; k < 32; ++k) v = fmaf(w2[o * 32 + k], h[k], v);
            vv[u] = fmaxf(v, 0.f);
        }
        out4[o4] = make_float4(vv[0], vv[1], vv[2], vv[3]);
    }
}

// ---------------------------------------------------------------- attention (bf16 MFMA)
// wave = 1 point at a time (8 points per wave); rows m = neighbor j (15 + 1
// masked), layer1: H(16x128) = fk(16x64) x W1^T, layer2: L(16x64) = relu(H) x
// W2^T. Verified gfx950 layouts: A[m=lane&15][k=quad*8+i], B[n=lane&15]
// [k=quad*8+i], C/D[col=lane&15][row=quad*4+reg]. Weights in VGPR bf16 frags,
// H transits LDS (C->A layout), softmax via quad-crossing shfl_xor.
__global__ __launch_bounds__(256, 2) void attn_kernel(
    const float* __restrict__ f1, const int* __restrict__ idx,
    const float* __restrict__ aw1, const float* __restrict__ ab1,
    const float* __restrict__ aw2, const float* __restrict__ ab2,
    float* __restrict__ fagg)
{
    __shared__ __align__(16) ushort fkb[4][16][72];    // 9.2 KB (stride 144 B)
    __shared__ __align__(16) ushort hb[4][16][136];    // 17.4 KB (stride 272 B)

    const int t = threadIdx.x;
    const int wv = t >> 6, lane = t & 63;
    const int l15 = lane & 15, qd = lane >> 4;

    // ---- preload weight B-frags (bf16), once per wave
    short8 w1f[8][2];
#pragma unroll
    for (int tile = 0; tile < 8; ++tile)
#pragma unroll
        for (int ks = 0; ks < 2; ++ks) {
            const float4* p = (const float4*)(aw1 + ((tile * 16 + l15) * 64 + ks * 32 + qd * 8));
            float4 A = p[0], B = p[1];
            short8 f;
            f[0] = f2bf(A.x); f[1] = f2bf(A.y); f[2] = f2bf(A.z); f[3] = f2bf(A.w);
            f[4] = f2bf(B.x); f[5] = f2bf(B.y); f[6] = f2bf(B.z); f[7] = f2bf(B.w);
            w1f[tile][ks] = f;
        }
    short8 w2f[4][4];
#pragma unroll
    for (int tile = 0; tile < 4; ++tile)
#pragma unroll
        for (int ks = 0; ks < 4; ++ks) {
            const float4* p = (const float4*)(aw2 + ((tile * 16 + l15) * 128 + ks * 32 + qd * 8));
            float4 A = p[0], B = p[1];
            short8 f;
            f[0] = f2bf(A.x); f[1] = f2bf(A.y); f[2] = f2bf(A.z); f[3] = f2bf(A.w);
            f[4] = f2bf(B.x); f[5] = f2bf(B.y); f[6] = f2bf(B.z); f[7] = f2bf(B.w);
            w2f[tile][ks] = f;
        }

    const int W = blockIdx.x * 4 + wv;
    for (int g = 0; g < 8; ++g) {
        const int P = W * 8 + g;
        const int b = P >> 13;

        // ---- stage fk (lane = channel c)
        float fc = f1[(size_t)P * 64 + lane];
        float fn[15];
#pragma unroll
        for (int j = 0; j < 15; ++j) {
            int nb = idx[(size_t)P * KK + 1 + j];
            fn[j] = f1[((size_t)b * NN + nb) * 64 + lane];
        }
#pragma unroll
        for (int j = 0; j < 15; ++j) fkb[wv][j][lane] = f2bf(fn[j] - fc);
        fkb[wv][15][lane] = 0;

        // ---- A-frags for layer 1 (lane = (qd, l15))
        short8 a0 = *(const short8*)&fkb[wv][l15][qd * 8];
        short8 a1 = *(const short8*)&fkb[wv][l15][32 + qd * 8];

        // ---- layer 1 MFMA -> relu -> LDS (C-layout -> A-layout transit)
#pragma unroll
        for (int tile = 0; tile < 8; ++tile) {
            float bv = ab1[tile * 16 + l15];
            f32x4 acc = { bv, bv, bv, bv };
            acc = __builtin_amdgcn_mfma_f32_16x16x32_bf16(a0, w1f[tile][0], acc, 0, 0, 0);
            acc = __builtin_amdgcn_mfma_f32_16x16x32_bf16(a1, w1f[tile][1], acc, 0, 0, 0);
#pragma unroll
            for (int reg = 0; reg < 4; ++reg)
                hb[wv][qd * 4 + reg][tile * 16 + l15] = f2bf(fmaxf(acc[reg], 0.f));
        }

        // ---- layer 2 MFMA
        short8 a2[4];
#pragma unroll
        for (int ks = 0; ks < 4; ++ks)
            a2[ks] = *(const short8*)&hb[wv][l15][ks * 32 + qd * 8];

        f32x4 L[4];
#pragma unroll
        for (int tile = 0; tile < 4; ++tile) {
            float bv = ab2[tile * 16 + l15];
            f32x4 acc = { bv, bv, bv, bv };
#pragma unroll
            for (int ks = 0; ks < 4; ++ks)
                acc = __builtin_amdgcn_mfma_f32_16x16x32_bf16(a2[ks], w2f[tile][ks], acc, 0, 0, 0);
            L[tile] = acc;
        }

        // ---- softmax over rows m=0..14 (m = qd*4+reg; col c = tile*16+l15)
        float fa[4];
#pragma unroll
        for (int tile = 0; tile < 4; ++tile) {
            float m1 = -3.0e38f;
#pragma unroll
            for (int reg = 0; reg < 4; ++reg)
                if (qd * 4 + reg < 15) m1 = fmaxf(m1, L[tile][reg]);
            m1 = fmaxf(m1, __shfl_xor(m1, 16));
            m1 = fmaxf(m1, __shfl_xor(m1, 32));
            float e[4], ssum = 0.f;
#pragma unroll
            for (int reg = 0; reg < 4; ++reg) {
                bool valid = (qd * 4 + reg < 15);
                e[reg] = valid ? __expf(L[tile][reg] - m1) : 0.f;
                ssum += e[reg];
            }
            ssum += __shfl_xor(ssum, 16);
            ssum += __shfl_xor(ssum, 32);
            float part = 0.f;
#pragma unroll
            for (int reg = 0; reg < 4; ++reg) {
                float fkv = bf2f(fkb[wv][qd * 4 + reg][tile * 16 + l15]);
                part = fmaf(e[reg], fkv, part);
            }
            part += __shfl_xor(part, 16);
            part += __shfl_xor(part, 32);
            fa[tile] = part / ssum;
        }
        if (qd == 0) {
#pragma unroll
            for (int tile = 0; tile < 4; ++tile)
                fagg[(size_t)P * 64 + tile * 16 + l15] = fa[tile];
        }
    }
}

// ---------------------------------------------------------------- cov + mlp2
__global__ __launch_bounds__(128) void cov_kernel(
    const float4* __restrict__ pts4, const int* __restrict__ idx,
    const float* __restrict__ w, const float* __restrict__ bb,
    float* __restrict__ fcov)
{
    int P = blockIdx.x * 128 + threadIdx.x;
    if (P >= BB * NN) return;
    int b = P >> 13;
    const int4* ip4 = (const int4*)(idx + (size_t)P * KK);
    int ids[KK];
#pragma unroll
    for (int g = 0; g < 4; ++g) {
        int4 v = ip4[g];
        ids[g * 4 + 0] = v.x; ids[g * 4 + 1] = v.y;
        ids[g * 4 + 2] = v.z; ids[g * 4 + 3] = v.w;
    }
    float px[KK], py[KK], pz[KK];
#pragma unroll
    for (int k = 0; k < KK; ++k) {
        float4 c = pts4[b * NN + ids[k]];
        px[k] = c.x; py[k] = c.y; pz[k] = c.z;
    }
    float mx = 0.f, my = 0.f, mz = 0.f;
#pragma unroll
    for (int k = 0; k < KK; ++k) { mx += px[k]; my += py[k]; mz += pz[k]; }
    mx *= (1.f / 16.f); my *= (1.f / 16.f); mz *= (1.f / 16.f);
    float c00 = 0, c01 = 0, c02 = 0, c11 = 0, c12 = 0, c22 = 0;
#pragma unroll
    for (int k = 0; k < KK; ++k) {
        float dx = px[k] - mx, dy = py[k] - my, dz = pz[k] - mz;
        c00 = fmaf(dx, dx, c00); c01 = fmaf(dx, dy, c01); c02 = fmaf(dx, dz, c02);
        c11 = fmaf(dy, dy, c11); c12 = fmaf(dy, dz, c12); c22 = fmaf(dz, dz, c22);
    }
    const float inv = 1.f / 16.f;
    float cf[9] = { c00 * inv, c01 * inv, c02 * inv,
                    c01 * inv, c11 * inv, c12 * inv,
                    c02 * inv, c12 * inv, c22 * inv };
    float* out = fcov + (size_t)P * 32;
#pragma unroll
    for (int o = 0; o < 32; ++o) {
        float v = bb[o];
#pragma unroll
        for (int m = 0; m < 9; ++m) v = fmaf(w[o * 9 + m], cf[m], v);
        out[o] = fmaxf(v, 0.f);
    }
}

// ---------------------------------------------------------------- mlp3 + output (4-way r-split)
__global__ __launch_bounds__(256) void mlp3_kernel(
    const float* __restrict__ fagg, const float* __restrict__ fcov,
    const float* __restrict__ w1, const float* __restrict__ b1,
    const float* __restrict__ w2t, const float* __restrict__ b2,
    const float* __restrict__ x, float* __restrict__ out)
{
    __shared__ float pacc[64][4][12];
    int t = threadIdx.x;
    int pl = t >> 2, qr = t & 3;
    int P = blockIdx.x * 64 + pl;
    int b = P >> 13, n = P & (NN - 1);

    float f[96];
    const float4* fa4 = (const float4*)(fagg + (size_t)P * 64);
#pragma unroll
    for (int g = 0; g < 16; ++g) {
        float4 v = fa4[g];
        f[g * 4 + 0] = v.x; f[g * 4 + 1] = v.y; f[g * 4 + 2] = v.z; f[g * 4 + 3] = v.w;
    }
    const float4* fc4 = (const float4*)(fcov + (size_t)P * 32);
#pragma unroll
    for (int g = 0; g < 8; ++g) {
        float4 v = fc4[g];
        f[64 + g * 4 + 0] = v.x; f[64 + g * 4 + 1] = v.y;
        f[64 + g * 4 + 2] = v.z; f[64 + g * 4 + 3] = v.w;
    }
    float acc[12];
#pragma unroll
    for (int o = 0; o < 12; ++o) acc[o] = 0.f;
    for (int rr = 0; rr < 32; ++rr) {
        int r = qr * 32 + rr;
        const float4* wr4 = (const float4*)(w1 + (size_t)r * 96);
        float s0 = 0.f, s1 = 0.f, s2 = 0.f, s3 = 0.f;
#pragma unroll
        for (int k4 = 0; k4 < 24; ++k4) {
            float4 wv = wr4[k4];
            s0 = fmaf(wv.x, f[k4 * 4 + 0], s0);
            s1 = fmaf(wv.y, f[k4 * 4 + 1], s1);
            s2 = fmaf(wv.z, f[k4 * 4 + 2], s2);
            s3 = fmaf(wv.w, f[k4 * 4 + 3], s3);
        }
        float h = fmaxf(b1[r] + ((s0 + s1) + (s2 + s3)), 0.f);
        const float4* w2r4 = (const float4*)(w2t + (size_t)r * 12);
#pragma unroll
        for (int g = 0; g < 3; ++g) {
            float4 wv = w2r4[g];
            acc[g * 4 + 0] = fmaf(wv.x, h, acc[g * 4 + 0]);
            acc[g * 4 + 1] = fmaf(wv.y, h, acc[g * 4 + 1]);
            acc[g * 4 + 2] = fmaf(wv.z, h, acc[g * 4 + 2]);
            acc[g * 4 + 3] = fmaf(wv.w, h, acc[g * 4 + 3]);
        }
    }
#pragma unroll
    for (int o = 0; o < 12; ++o) pacc[pl][qr][o] = acc[o];
    __syncthreads();
    if (qr == 0) {
#pragma unroll
        for (int i = 0; i < 12; ++i) {
            float v = b2[i] + ((pacc[pl][0][i] + pacc[pl][1][i]) + (pacc[pl][2][i] + pacc[pl][3][i]));
            int c = i >> 2, rr = i & 3;
            float xv = x[((size_t)b * 3 + c) * NN + n];
            out[(((size_t)b * 3 + c) * 4 + rr) * NN + n] = xv + 0.15f * v;
        }
    }
}

// ---------------------------------------------------------------- launch
extern "C" void kernel_launch(void* const* d_in, const int* in_sizes, int n_in,
                              void* d_out, int out_size, void* d_ws, size_t ws_size,
                              hipStream_t stream)
{
    (void)in_sizes; (void)n_in; (void)out_size; (void)ws_size;
    const float* x    = (const float*)d_in[0];
    const float* m1w1 = (const float*)d_in[1];
    const float* m1b1 = (const float*)d_in[2];
    const float* m1w2 = (const float*)d_in[3];
    const float* m1b2 = (const float*)d_in[4];
    const float* m2w1 = (const float*)d_in[5];
    const float* m2b1 = (const float*)d_in[6];
    const float* m3w1 = (const float*)d_in[7];
    const float* m3b1 = (const float*)d_in[8];
    const float* m3w2 = (const float*)d_in[9];
    const float* m3b2 = (const float*)d_in[10];
    const float* aw1  = (const float*)d_in[11];
    const float* ab1  = (const float*)d_in[12];
    const float* aw2  = (const float*)d_in[13];
    const float* ab2  = (const float*)d_in[14];
    float* out = (float*)d_out;

    char* ws = (char*)d_ws;
    float4* pts4 = (float4*)(ws + 0);             //   262144 B
    ull*    thrb = (ull*)  (ws + 262144);         //   131072 B
    int*    idxb = (int*)  (ws + 393216);         //  1048576 B
    int*    cntb = (int*)  (ws + 1441792);        //   524288 B
    ushort* bufb = (ushort*)(ws + 1966080);       //  8388608 B
    float*  f1   = (float*)(ws + 10354688);       //  4194304 B
    float*  fagg = (float*)(ws + 14548992);       //  4194304 B
    float*  fcov = (float*)(ws + 18743296);       //  2097152 B
    float*  w3bt = (float*)(ws + 20840448);       //     6144 B

    prep_kernel<<<64, 256, 0, stream>>>(x, pts4, m3w2, w3bt);
    knn_prefix_kernel<<<dim3(NN / QPB, BB), 512, 0, stream>>>(pts4, thrb);
    knn_scan_kernel<<<dim3(NN / QPB, BB), 512, 0, stream>>>(pts4, thrb, bufb, cntb);
    knn_select_kernel<<<256, 256, 0, stream>>>(pts4, bufb, cntb, idxb);
    f1_kernel<<<128, 128, 0, stream>>>(x, m1w1, m1b1, m1w2, m1b2, f1);
    attn_kernel<<<512, 256, 0, stream>>>(f1, idxb, aw1, ab1, aw2, ab2, fagg);
    cov_kernel<<<128, 128, 0, stream>>>(pts4, idxb, m2w1, m2b1, fcov);
    mlp3_kernel<<<256, 256, 0, stream>>>(fagg, fcov, m3w1, m3b1, w3bt, m3b2, x, out);
}

// Round 5
// 440.751 us; speedup vs baseline: 2.3690x; 1.1242x over previous
//
#include <hip/hip_runtime.h>

#define BB 2
#define NN 8192
#define KK 16
#define QPB 64
#define PENDCAP 16
#define PRE 256          // prefix candidates sampled per 1024-slice (8 -> 2048 sample)
#define NSL 16           // K2/K3 subslices per query
#define CAP 16           // buffered survivors per (query, subslice)
typedef unsigned long long ull;
typedef unsigned short ushort;
#define KINF 0xFFFFFFFFFFFFFFFFULL

typedef __attribute__((ext_vector_type(8))) short short8;
typedef __attribute__((ext_vector_type(4))) float f32x4;

static __device__ __forceinline__ ushort f2bf(float f) {
    unsigned u = __float_as_uint(f);
    unsigned r = (u + 0x7FFFu + ((u >> 16) & 1u)) >> 16;
    return (ushort)r;
}
static __device__ __forceinline__ float bf2f(ushort s) {
    return __uint_as_float(((unsigned)s) << 16);
}

// ---------------------------------------------------------------- prep
__global__ __launch_bounds__(256) void prep_kernel(
    const float* __restrict__ x, float4* __restrict__ pts4,
    const float* __restrict__ m3w2, float* __restrict__ w3bt)
{
    int t = blockIdx.x * 256 + threadIdx.x;
    if (t < BB * NN) {
        int b = t >> 13, n = t & (NN - 1);
        float x0 = x[(b * 3 + 0) * NN + n];
        float x1 = x[(b * 3 + 1) * NN + n];
        float x2 = x[(b * 3 + 2) * NN + n];
        // same fmaf chain as the knn dot so that d(self) == 0 bit-exactly
        float sq = fmaf(x2, x2, fmaf(x1, x1, __fmul_rn(x0, x0)));
        pts4[t] = make_float4(x0, x1, x2, sq);
    }
    if (t < 128 * 12) {           // w3bt[r*12+o] = m3w2[o*128+r]
        int r = t / 12, o = t - r * 12;
        w3bt[t] = m3w2[o * 128 + r];
    }
}

// ---------------------------------------------------------------- knn K1: prefix -> conservative per-query threshold (float)
// 512 thr = 8 waves; wave w samples first PRE of slice-w (1024 wide); float
// top-16 via deferred-drain; 8x16 merge -> 16th smallest distance. thr >=
// true d16, so K2's survivor set is a superset of the true top-16.
__global__ __launch_bounds__(512) void knn_prefix_kernel(
    const float4* __restrict__ pts4, float* __restrict__ thrb)
{
    __shared__ float smem[PENDCAP * 512];   // 32 KB

    const int t    = threadIdx.x;
    const int wv   = t >> 6;
    const int lane = t & 63;
    const int b    = blockIdx.y;
    const int q    = blockIdx.x * QPB + lane;
    const int sl   = __builtin_amdgcn_readfirstlane(wv);

    const float4 qp = pts4[b * NN + q];
    const float4* __restrict__ cp = pts4 + (size_t)b * NN + (size_t)sl * 1024;

    float list[KK];
#pragma unroll
    for (int i = 0; i < KK; ++i) list[i] = 3.0e38f;
    float curmax = 3.0e38f;
    int pend = 0;

    for (int i0 = 0; i0 < PRE; i0 += 8) {
#pragma unroll
        for (int u = 0; u < 8; ++u) {
            float4 c = cp[i0 + u];
            float dot = fmaf(qp.z, c.z, fmaf(qp.y, c.y, __fmul_rn(qp.x, c.x)));
            float d = __fadd_rn(__fsub_rn(qp.w, __fmul_rn(2.0f, dot)), c.w);
            smem[(size_t)pend * 512 + t] = d;        // branchless push
            pend += (d < curmax) ? 1 : 0;
        }
        if (__any(pend >= 8)) {
            for (int j = 0; j < PENDCAP - 1; ++j) {
                if (!__any(j < pend)) break;
                float v = smem[(size_t)j * 512 + t];
                float k = (j < pend) ? v : 3.0e38f;
#pragma unroll
                for (int i = KK - 1; i > 0; --i) {
                    bool c1 = k < list[i];
                    bool c2 = k < list[i - 1];
                    float nd = c2 ? list[i - 1] : k;
                    list[i] = c1 ? nd : list[i];
                }
                list[0] = (k < list[0]) ? k : list[0];
            }
            pend = 0;
            curmax = list[KK - 1];
        }
    }
    for (int j = 0; j < PENDCAP - 1; ++j) {
        if (!__any(j < pend)) break;
        float v = smem[(size_t)j * 512 + t];
        float k = (j < pend) ? v : 3.0e38f;
#pragma unroll
        for (int i = KK - 1; i > 0; --i) {
            bool c1 = k < list[i];
            bool c2 = k < list[i - 1];
            float nd = c2 ? list[i - 1] : k;
            list[i] = c1 ? nd : list[i];
        }
        list[0] = (k < list[0]) ? k : list[0];
    }

    __syncthreads();
#pragma unroll
    for (int j = 0; j < KK; ++j) smem[(size_t)((wv * KK + j) * 64 + lane)] = list[j];
    __syncthreads();

    if (t < QPB) {
        float h[8];
        int kc[8];
#pragma unroll
        for (int s = 0; s < 8; ++s) { h[s] = smem[(size_t)((s * KK) * 64 + t)]; kc[s] = 0; }
        float best = 3.0e38f;
        for (int o = 0; o < KK; ++o) {
            best = h[0]; int bs = 0;
#pragma unroll
            for (int s = 1; s < 8; ++s) { if (h[s] < best) { best = h[s]; bs = s; } }
#pragma unroll
            for (int s = 0; s < 8; ++s) {
                if (s == bs) {
                    kc[s]++;
                    h[s] = (kc[s] < KK) ? smem[(size_t)((s * KK + kc[s]) * 64 + t)] : 3.0e38f;
                }
            }
        }
        thrb[(size_t)b * NN + blockIdx.x * QPB + t] = best;   // 16th smallest of sample
    }
}

// ---------------------------------------------------------------- knn K2: full scan vs float threshold
// grid (128,2,2) x 8 waves = 4096 waves; wave = subslice s = z*8+wv, 512
// candidates, 64 queries/lane-parallel. Survivors (d <= thr) buffered.
__global__ __launch_bounds__(512) void knn_scan_kernel(
    const float4* __restrict__ pts4, const float* __restrict__ thrb,
    ushort* __restrict__ buf, ushort* __restrict__ cnt)
{
    const int t    = threadIdx.x;
    const int wv   = t >> 6;
    const int lane = t & 63;
    const int b    = blockIdx.y;
    const int q    = blockIdx.x * QPB + lane;          // within batch
    const int s    = __builtin_amdgcn_readfirstlane(blockIdx.z * 8 + wv);

    const float4 qp = pts4[b * NN + q];
    const float thr = thrb[(size_t)b * NN + q];
    const float4* __restrict__ cp = pts4 + (size_t)b * NN + (size_t)s * 512;
    const unsigned cbase = s * 512;

    const int cell = (((int)(b * NN) + q) << 4) + s;   // (global q)*16 + subslice
    ushort* __restrict__ bp = buf + (size_t)cell * CAP;
    int pend = 0;

    for (int i0 = 0; i0 < 512; i0 += 8) {
#pragma unroll
        for (int u = 0; u < 8; ++u) {
            const int ci = i0 + u;
            float4 c = cp[ci];
            float dot = fmaf(qp.z, c.z, fmaf(qp.y, c.y, __fmul_rn(qp.x, c.x)));
            float d = __fadd_rn(__fsub_rn(qp.w, __fmul_rn(2.0f, dot)), c.w);
            if (d <= thr) {
                if (pend < CAP) bp[pend] = (ushort)(cbase + ci);
                pend++;
            }
        }
    }
    cnt[cell] = (ushort)((pend < CAP) ? pend : CAP);
}

// ---------------------------------------------------------------- knn K3: exact select of survivors
// 256 thr = 4 waves; wave = 16 queries x 4 lanes (4 cells each); recompute
// exact ull keys (idx tie-break), sorted-insert, 4-way merge -> final idx.
__global__ __launch_bounds__(256) void knn_select_kernel(
    const float4* __restrict__ pts4, const ushort* __restrict__ buf,
    const ushort* __restrict__ cnt, int* __restrict__ iout)
{
    __shared__ ull sm3[4][4][16][KK];   // 32 KB

    const int t = threadIdx.x;
    const int wv = t >> 6, lane = t & 63;
    const int qq = lane & 15, hh = lane >> 4;
    const int q  = (blockIdx.x * 4 + wv) * 16 + qq;    // global query 0..16383
    const int b  = q >> 13;

    const float4 qp = pts4[q];
    ull list[KK];
#pragma unroll
    for (int i = 0; i < KK; ++i) list[i] = KINF;

#pragma unroll
    for (int ss = 0; ss < 4; ++ss) {
        const int s = hh * 4 + ss;
        const int cell = (q << 4) + s;
        const int n = cnt[cell];
        const ushort* bp = buf + (size_t)cell * CAP;
        for (int i = 0; i < n; ++i) {
            int id = bp[i];
            float4 c = pts4[b * NN + id];
            float dot = fmaf(qp.z, c.z, fmaf(qp.y, c.y, __fmul_rn(qp.x, c.x)));
            float d = __fadd_rn(__fsub_rn(qp.w, __fmul_rn(2.0f, dot)), c.w);
            unsigned ud = __float_as_uint(d);
            ud ^= ((unsigned)((int)ud >> 31)) | 0x80000000u;
            ull k = ((ull)ud << 32) | (unsigned)id;
#pragma unroll
            for (int i2 = KK - 1; i2 > 0; --i2) {
                bool c1 = k < list[i2];
                bool c2 = k < list[i2 - 1];
                ull nd = c2 ? list[i2 - 1] : k;
                list[i2] = c1 ? nd : list[i2];
            }
            list[0] = (k < list[0]) ? k : list[0];
        }
    }

#pragma unroll
    for (int k = 0; k < KK; ++k) sm3[wv][hh][qq][k] = list[k];

    if (hh == 0) {
        ull h[4]; int kc[4];
#pragma unroll
        for (int s = 0; s < 4; ++s) { h[s] = sm3[wv][s][qq][0]; kc[s] = 0; }
        int* op = iout + (size_t)q * KK;
        for (int o = 0; o < KK; ++o) {
            ull best = h[0]; int bs = 0;
#pragma unroll
            for (int s = 1; s < 4; ++s) { if (h[s] < best) { best = h[s]; bs = s; } }
            op[o] = (int)(unsigned)(best & 0xFFFFFFFFULL);
#pragma unroll
            for (int s = 0; s < 4; ++s) {
                if (s == bs) {
                    kc[s]++;
                    h[s] = (kc[s] < KK) ? sm3[wv][s][qq][kc[s]] : KINF;
                }
            }
        }
    }
}

// ---------------------------------------------------------------- f1
__global__ __launch_bounds__(128) void f1_kernel(
    const float* __restrict__ x,
    const float* __restrict__ w1, const float* __restrict__ b1,
    const float* __restrict__ w2, const float* __restrict__ b2,
    float* __restrict__ f1)
{
    int P = blockIdx.x * 128 + threadIdx.x;
    if (P >= BB * NN) return;
    int b = P >> 13, n = P & (NN - 1);
    float x0 = x[(b * 3 + 0) * NN + n];
    float x1 = x[(b * 3 + 1) * NN + n];
    float x2 = x[(b * 3 + 2) * NN + n];
    float h[32];
#pragma unroll
    for (int o = 0; o < 32; ++o) {
        float v = fmaf(w1[o * 3 + 2], x2, fmaf(w1[o * 3 + 1], x1, fmaf(w1[o * 3 + 0], x0, b1[o])));
        h[o] = fmaxf(v, 0.f);
    }
    float4* out4 = (float4*)(f1 + (size_t)P * 64);
#pragma unroll
    for (int o4 = 0; o4 < 16; ++o4) {
        float vv[4];
#pragma unroll
        for (int u = 0; u < 4; ++u) {
            int o = o4 * 4 + u;
            float v = b2[o];
#pragma unroll
            for (int k = 0; k < 32; ++k) v = fmaf(w2[o * 32 + k], h[k], v);
            vv[u] = fmaxf(v, 0.f);
        }
        out4[o4] = make_float4(vv[0], vv[1], vv[2], vv[3]);
    }
}

// ---------------------------------------------------------------- attention (bf16 MFMA) — verified round 4
__global__ __launch_bounds__(256, 2) void attn_kernel(
    const float* __restrict__ f1, const int* __restrict__ idx,
    const float* __restrict__ aw1, const float* __restrict__ ab1,
    const float* __restrict__ aw2, const float* __restrict__ ab2,
    float* __restrict__ fagg)
{
    __shared__ __align__(16) ushort fkb[4][16][72];    // stride 144 B
    __shared__ __align__(16) ushort hb[4][16][136];    // stride 272 B

    const int t = threadIdx.x;
    const int wv = t >> 6, lane = t & 63;
    const int l15 = lane & 15, qd = lane >> 4;

    short8 w1f[8][2];
#pragma unroll
    for (int tile = 0; tile < 8; ++tile)
#pragma unroll
        for (int ks = 0; ks < 2; ++ks) {
            const float4* p = (const float4*)(aw1 + ((tile * 16 + l15) * 64 + ks * 32 + qd * 8));
            float4 A = p[0], B = p[1];
            short8 f;
            f[0] = f2bf(A.x); f[1] = f2bf(A.y); f[2] = f2bf(A.z); f[3] = f2bf(A.w);
            f[4] = f2bf(B.x); f[5] = f2bf(B.y); f[6] = f2bf(B.z); f[7] = f2bf(B.w);
            w1f[tile][ks] = f;
        }
    short8 w2f[4][4];
#pragma unroll
    for (int tile = 0; tile < 4; ++tile)
#pragma unroll
        for (int ks = 0; ks < 4; ++ks) {
            const float4* p = (const float4*)(aw2 + ((tile * 16 + l15) * 128 + ks * 32 + qd * 8));
            float4 A = p[0], B = p[1];
            short8 f;
            f[0] = f2bf(A.x); f[1] = f2bf(A.y); f[2] = f2bf(A.z); f[3] = f2bf(A.w);
            f[4] = f2bf(B.x); f[5] = f2bf(B.y); f[6] = f2bf(B.z); f[7] = f2bf(B.w);
            w2f[tile][ks] = f;
        }

    const int W = blockIdx.x * 4 + wv;
    for (int g = 0; g < 8; ++g) {
        const int P = W * 8 + g;
        const int b = P >> 13;

        float fc = f1[(size_t)P * 64 + lane];
        float fn[15];
#pragma unroll
        for (int j = 0; j < 15; ++j) {
            int nb = idx[(size_t)P * KK + 1 + j];
            fn[j] = f1[((size_t)b * NN + nb) * 64 + lane];
        }
#pragma unroll
        for (int j = 0; j < 15; ++j) fkb[wv][j][lane] = f2bf(fn[j] - fc);
        fkb[wv][15][lane] = 0;

        short8 a0 = *(const short8*)&fkb[wv][l15][qd * 8];
        short8 a1 = *(const short8*)&fkb[wv][l15][32 + qd * 8];

#pragma unroll
        for (int tile = 0; tile < 8; ++tile) {
            float bv = ab1[tile * 16 + l15];
            f32x4 acc = { bv, bv, bv, bv };
            acc = __builtin_amdgcn_mfma_f32_16x16x32_bf16(a0, w1f[tile][0], acc, 0, 0, 0);
            acc = __builtin_amdgcn_mfma_f32_16x16x32_bf16(a1, w1f[tile][1], acc, 0, 0, 0);
#pragma unroll
            for (int reg = 0; reg < 4; ++reg)
                hb[wv][qd * 4 + reg][tile * 16 + l15] = f2bf(fmaxf(acc[reg], 0.f));
        }

        short8 a2[4];
#pragma unroll
        for (int ks = 0; ks < 4; ++ks)
            a2[ks] = *(const short8*)&hb[wv][l15][ks * 32 + qd * 8];

        f32x4 L[4];
#pragma unroll
        for (int tile = 0; tile < 4; ++tile) {
            float bv = ab2[tile * 16 + l15];
            f32x4 acc = { bv, bv, bv, bv };
#pragma unroll
            for (int ks = 0; ks < 4; ++ks)
                acc = __builtin_amdgcn_mfma_f32_16x16x32_bf16(a2[ks], w2f[tile][ks], acc, 0, 0, 0);
            L[tile] = acc;
        }

        float fa[4];
#pragma unroll
        for (int tile = 0; tile < 4; ++tile) {
            float m1 = -3.0e38f;
#pragma unroll
            for (int reg = 0; reg < 4; ++reg)
                if (qd * 4 + reg < 15) m1 = fmaxf(m1, L[tile][reg]);
            m1 = fmaxf(m1, __shfl_xor(m1, 16));
            m1 = fmaxf(m1, __shfl_xor(m1, 32));
            float e[4], ssum = 0.f;
#pragma unroll
            for (int reg = 0; reg < 4; ++reg) {
                bool valid = (qd * 4 + reg < 15);
                e[reg] = valid ? __expf(L[tile][reg] - m1) : 0.f;
                ssum += e[reg];
            }
            ssum += __shfl_xor(ssum, 16);
            ssum += __shfl_xor(ssum, 32);
            float part = 0.f;
#pragma unroll
            for (int reg = 0; reg < 4; ++reg) {
                float fkv = bf2f(fkb[wv][qd * 4 + reg][tile * 16 + l15]);
                part = fmaf(e[reg], fkv, part);
            }
            part += __shfl_xor(part, 16);
            part += __shfl_xor(part, 32);
            fa[tile] = part / ssum;
        }
        if (qd == 0) {
#pragma unroll
            for (int tile = 0; tile < 4; ++tile)
                fagg[(size_t)P * 64 + tile * 16 + l15] = fa[tile];
        }
    }
}

// ---------------------------------------------------------------- cov + mlp2
__global__ __launch_bounds__(128) void cov_kernel(
    const float4* __restrict__ pts4, const int* __restrict__ idx,
    const float* __restrict__ w, const float* __restrict__ bb,
    float* __restrict__ fcov)
{
    int P = blockIdx.x * 128 + threadIdx.x;
    if (P >= BB * NN) return;
    int b = P >> 13;
    const int4* ip4 = (const int4*)(idx + (size_t)P * KK);
    int ids[KK];
#pragma unroll
    for (int g = 0; g < 4; ++g) {
        int4 v = ip4[g];
        ids[g * 4 + 0] = v.x; ids[g * 4 + 1] = v.y;
        ids[g * 4 + 2] = v.z; ids[g * 4 + 3] = v.w;
    }
    float px[KK], py[KK], pz[KK];
#pragma unroll
    for (int k = 0; k < KK; ++k) {
        float4 c = pts4[b * NN + ids[k]];
        px[k] = c.x; py[k] = c.y; pz[k] = c.z;
    }
    float mx = 0.f, my = 0.f, mz = 0.f;
#pragma unroll
    for (int k = 0; k < KK; ++k) { mx += px[k]; my += py[k]; mz += pz[k]; }
    mx *= (1.f / 16.f); my *= (1.f / 16.f); mz *= (1.f / 16.f);
    float c00 = 0, c01 = 0, c02 = 0, c11 = 0, c12 = 0, c22 = 0;
#pragma unroll
    for (int k = 0; k < KK; ++k) {
        float dx = px[k] - mx, dy = py[k] - my, dz = pz[k] - mz;
        c00 = fmaf(dx, dx, c00); c01 = fmaf(dx, dy, c01); c02 = fmaf(dx, dz, c02);
        c11 = fmaf(dy, dy, c11); c12 = fmaf(dy, dz, c12); c22 = fmaf(dz, dz, c22);
    }
    const float inv = 1.f / 16.f;
    float cf[9] = { c00 * inv, c01 * inv, c02 * inv,
                    c01 * inv, c11 * inv, c12 * inv,
                    c02 * inv, c12 * inv, c22 * inv };
    float* out = fcov + (size_t)P * 32;
#pragma unroll
    for (int o = 0; o < 32; ++o) {
        float v = bb[o];
#pragma unroll
        for (int m = 0; m < 9; ++m) v = fmaf(w[o * 9 + m], cf[m], v);
        out[o] = fmaxf(v, 0.f);
    }
}

// ---------------------------------------------------------------- mlp3 + output
// thread per point, wave-uniform r-loop -> weight loads scalarize (s_load)
__global__ __launch_bounds__(128, 2) void mlp3_kernel(
    const float* __restrict__ fagg, const float* __restrict__ fcov,
    const float* __restrict__ w1, const float* __restrict__ b1,
    const float* __restrict__ w2t, const float* __restrict__ b2,
    const float* __restrict__ x, float* __restrict__ out)
{
    int P = blockIdx.x * 128 + threadIdx.x;
    if (P >= BB * NN) return;
    int b = P >> 13, n = P & (NN - 1);
    float f[96];
    const float4* fa4 = (const float4*)(fagg + (size_t)P * 64);
#pragma unroll
    for (int g = 0; g < 16; ++g) {
        float4 v = fa4[g];
        f[g * 4 + 0] = v.x; f[g * 4 + 1] = v.y; f[g * 4 + 2] = v.z; f[g * 4 + 3] = v.w;
    }
    const float4* fc4 = (const float4*)(fcov + (size_t)P * 32);
#pragma unroll
    for (int g = 0; g < 8; ++g) {
        float4 v = fc4[g];
        f[64 + g * 4 + 0] = v.x; f[64 + g * 4 + 1] = v.y;
        f[64 + g * 4 + 2] = v.z; f[64 + g * 4 + 3] = v.w;
    }
    float acc[12];
#pragma unroll
    for (int o = 0; o < 12; ++o) acc[o] = b2[o];
    for (int r = 0; r < 128; ++r) {
        const float4* wr4 = (const float4*)(w1 + (size_t)r * 96);
        float s0 = 0.f, s1 = 0.f, s2 = 0.f, s3 = 0.f;
#pragma unroll
        for (int k4 = 0; k4 < 24; ++k4) {
            float4 wv = wr4[k4];
            s0 = fmaf(wv.x, f[k4 * 4 + 0], s0);
            s1 = fmaf(wv.y, f[k4 * 4 + 1], s1);
            s2 = fmaf(wv.z, f[k4 * 4 + 2], s2);
            s3 = fmaf(wv.w, f[k4 * 4 + 3], s3);
        }
        float h = fmaxf(b1[r] + ((s0 + s1) + (s2 + s3)), 0.f);
        const float4* w2r4 = (const float4*)(w2t + (size_t)r * 12);
#pragma unroll
        for (int g = 0; g < 3; ++g) {
            float4 wv = w2r4[g];
            acc[g * 4 + 0] = fmaf(wv.x, h, acc[g * 4 + 0]);
            acc[g * 4 + 1] = fmaf(wv.y, h, acc[g * 4 + 1]);
            acc[g * 4 + 2] = fmaf(wv.z, h, acc[g * 4 + 2]);
            acc[g * 4 + 3] = fmaf(wv.w, h, acc[g * 4 + 3]);
        }
    }
#pragma unroll
    for (int i = 0; i < 12; ++i) {
        int c = i >> 2, rr = i & 3;
        float xv = x[((size_t)b * 3 + c) * NN + n];
        out[(((size_t)b * 3 + c) * 4 + rr) * NN + n] = xv + 0.15f * acc[i];
    }
}

// ---------------------------------------------------------------- launch
extern "C" void kernel_launch(void* const* d_in, const int* in_sizes, int n_in,
                              void* d_out, int out_size, void* d_ws, size_t ws_size,
                              hipStream_t stream)
{
    (void)in_sizes; (void)n_in; (void)out_size; (void)ws_size;
    const float* x    = (const float*)d_in[0];
    const float* m1w1 = (const float*)d_in[1];
    const float* m1b1 = (const float*)d_in[2];
    const float* m1w2 = (const float*)d_in[3];
    const float* m1b2 = (const float*)d_in[4];
    const float* m2w1 = (const float*)d_in[5];
    const float* m2b1 = (const float*)d_in[6];
    const float* m3w1 = (const float*)d_in[7];
    const float* m3b1 = (const float*)d_in[8];
    const float* m3w2 = (const float*)d_in[9];
    const float* m3b2 = (const float*)d_in[10];
    const float* aw1  = (const float*)d_in[11];
    const float* ab1  = (const float*)d_in[12];
    const float* aw2  = (const float*)d_in[13];
    const float* ab2  = (const float*)d_in[14];
    float* out = (float*)d_out;

    char* ws = (char*)d_ws;
    float4* pts4 = (float4*)(ws + 0);             //   262144 B
    float*  thrb = (float*)(ws + 262144);         //    65536 B
    int*    idxb = (int*)  (ws + 327680);         //  1048576 B
    ushort* cntb = (ushort*)(ws + 1376256);       //   524288 B
    ushort* bufb = (ushort*)(ws + 1900544);       //  8388608 B
    float*  f1   = (float*)(ws + 10289152);       //  4194304 B
    float*  fagg = (float*)(ws + 14483456);       //  4194304 B
    float*  fcov = (float*)(ws + 18677760);       //  2097152 B
    float*  w3bt = (float*)(ws + 20774912);       //     6144 B

    prep_kernel<<<64, 256, 0, stream>>>(x, pts4, m3w2, w3bt);
    knn_prefix_kernel<<<dim3(NN / QPB, BB), 512, 0, stream>>>(pts4, thrb);
    knn_scan_kernel<<<dim3(NN / QPB, BB, 2), 512, 0, stream>>>(pts4, thrb, bufb, cntb);
    knn_select_kernel<<<256, 256, 0, stream>>>(pts4, bufb, cntb, idxb);
    f1_kernel<<<128, 128, 0, stream>>>(x, m1w1, m1b1, m1w2, m1b2, f1);
    attn_kernel<<<512, 256, 0, stream>>>(f1, idxb, aw1, ab1, aw2, ab2, fagg);
    cov_kernel<<<128, 128, 0, stream>>>(pts4, idxb, m2w1, m2b1, fcov);
    mlp3_kernel<<<128, 128, 0, stream>>>(fagg, fcov, m3w1, m3b1, w3bt, m3b2, x, out);
}

// Round 6
// 333.810 us; speedup vs baseline: 3.1280x; 1.3204x over previous
//
#include <hip/hip_runtime.h>

#define BB 2
#define NN 8192
#define KK 16
#define QPB 64
#define PENDCAP 16
#define PRE 256          // prefix candidates sampled per 1024-slice (8 -> 2048 sample)
#define CAP 16           // buffered survivors per (query, subslice)
typedef unsigned long long ull;
typedef unsigned short ushort;
#define KINF 0xFFFFFFFFFFFFFFFFULL

typedef __attribute__((ext_vector_type(8))) short short8;
typedef __attribute__((ext_vector_type(4))) float f32x4;

static __device__ __forceinline__ ushort f2bf(float f) {
    unsigned u = __float_as_uint(f);
    unsigned r = (u + 0x7FFFu + ((u >> 16) & 1u)) >> 16;
    return (ushort)r;
}
static __device__ __forceinline__ float bf2f(ushort s) {
    return __uint_as_float(((unsigned)s) << 16);
}

// ---------------------------------------------------------------- prep
__global__ __launch_bounds__(256) void prep_kernel(
    const float* __restrict__ x, float4* __restrict__ pts4)
{
    int t = blockIdx.x * 256 + threadIdx.x;
    if (t < BB * NN) {
        int b = t >> 13, n = t & (NN - 1);
        float x0 = x[(b * 3 + 0) * NN + n];
        float x1 = x[(b * 3 + 1) * NN + n];
        float x2 = x[(b * 3 + 2) * NN + n];
        // same fmaf chain as the knn dot so that d(self) == 0 bit-exactly
        float sq = fmaf(x2, x2, fmaf(x1, x1, __fmul_rn(x0, x0)));
        pts4[t] = make_float4(x0, x1, x2, sq);
    }
}

// ---------------------------------------------------------------- knn K1: prefix -> conservative per-query threshold (float)
__global__ __launch_bounds__(512) void knn_prefix_kernel(
    const float4* __restrict__ pts4, float* __restrict__ thrb)
{
    __shared__ float smem[PENDCAP * 512];   // 32 KB

    const int t    = threadIdx.x;
    const int wv   = t >> 6;
    const int lane = t & 63;
    const int b    = blockIdx.y;
    const int q    = blockIdx.x * QPB + lane;
    const int sl   = __builtin_amdgcn_readfirstlane(wv);

    const float4 qp = pts4[b * NN + q];
    const float4* __restrict__ cp = pts4 + (size_t)b * NN + (size_t)sl * 1024;

    float list[KK];
#pragma unroll
    for (int i = 0; i < KK; ++i) list[i] = 3.0e38f;
    float curmax = 3.0e38f;
    int pend = 0;

    for (int i0 = 0; i0 < PRE; i0 += 8) {
#pragma unroll
        for (int u = 0; u < 8; ++u) {
            float4 c = cp[i0 + u];
            float dot = fmaf(qp.z, c.z, fmaf(qp.y, c.y, __fmul_rn(qp.x, c.x)));
            float d = __fadd_rn(__fsub_rn(qp.w, __fmul_rn(2.0f, dot)), c.w);
            smem[(size_t)pend * 512 + t] = d;        // branchless push
            pend += (d < curmax) ? 1 : 0;
        }
        if (__any(pend >= 8)) {
            for (int j = 0; j < PENDCAP - 1; ++j) {
                if (!__any(j < pend)) break;
                float v = smem[(size_t)j * 512 + t];
                float k = (j < pend) ? v : 3.0e38f;
#pragma unroll
                for (int i = KK - 1; i > 0; --i) {
                    bool c1 = k < list[i];
                    bool c2 = k < list[i - 1];
                    float nd = c2 ? list[i - 1] : k;
                    list[i] = c1 ? nd : list[i];
                }
                list[0] = (k < list[0]) ? k : list[0];
            }
            pend = 0;
            curmax = list[KK - 1];
        }
    }
    for (int j = 0; j < PENDCAP - 1; ++j) {
        if (!__any(j < pend)) break;
        float v = smem[(size_t)j * 512 + t];
        float k = (j < pend) ? v : 3.0e38f;
#pragma unroll
        for (int i = KK - 1; i > 0; --i) {
            bool c1 = k < list[i];
            bool c2 = k < list[i - 1];
            float nd = c2 ? list[i - 1] : k;
            list[i] = c1 ? nd : list[i];
        }
        list[0] = (k < list[0]) ? k : list[0];
    }

    __syncthreads();
#pragma unroll
    for (int j = 0; j < KK; ++j) smem[(size_t)((wv * KK + j) * 64 + lane)] = list[j];
    __syncthreads();

    if (t < QPB) {
        float h[8];
        int kc[8];
#pragma unroll
        for (int s = 0; s < 8; ++s) { h[s] = smem[(size_t)((s * KK) * 64 + t)]; kc[s] = 0; }
        float best = 3.0e38f;
        for (int o = 0; o < KK; ++o) {
            best = h[0]; int bs = 0;
#pragma unroll
            for (int s = 1; s < 8; ++s) { if (h[s] < best) { best = h[s]; bs = s; } }
#pragma unroll
            for (int s = 0; s < 8; ++s) {
                if (s == bs) {
                    kc[s]++;
                    h[s] = (kc[s] < KK) ? smem[(size_t)((s * KK + kc[s]) * 64 + t)] : 3.0e38f;
                }
            }
        }
        thrb[(size_t)b * NN + blockIdx.x * QPB + t] = best;   // 16th smallest of sample
    }
}

// ---------------------------------------------------------------- knn K2: full scan vs float threshold
__global__ __launch_bounds__(512) void knn_scan_kernel(
    const float4* __restrict__ pts4, const float* __restrict__ thrb,
    ushort* __restrict__ buf, ushort* __restrict__ cnt)
{
    const int t    = threadIdx.x;
    const int wv   = t >> 6;
    const int lane = t & 63;
    const int b    = blockIdx.y;
    const int q    = blockIdx.x * QPB + lane;          // within batch
    const int s    = __builtin_amdgcn_readfirstlane(blockIdx.z * 8 + wv);

    const float4 qp = pts4[b * NN + q];
    const float thr = thrb[(size_t)b * NN + q];
    const float4* __restrict__ cp = pts4 + (size_t)b * NN + (size_t)s * 512;
    const unsigned cbase = s * 512;

    const int cell = (((int)(b * NN) + q) << 4) + s;   // (global q)*16 + subslice
    ushort* __restrict__ bp = buf + (size_t)cell * CAP;
    int pend = 0;

    for (int i0 = 0; i0 < 512; i0 += 8) {
#pragma unroll
        for (int u = 0; u < 8; ++u) {
            const int ci = i0 + u;
            float4 c = cp[ci];
            float dot = fmaf(qp.z, c.z, fmaf(qp.y, c.y, __fmul_rn(qp.x, c.x)));
            float d = __fadd_rn(__fsub_rn(qp.w, __fmul_rn(2.0f, dot)), c.w);
            if (d <= thr) {
                if (pend < CAP) bp[pend] = (ushort)(cbase + ci);
                pend++;
            }
        }
    }
    cnt[cell] = (ushort)((pend < CAP) ? pend : CAP);
}

// ---------------------------------------------------------------- knn K3: exact select of survivors
__global__ __launch_bounds__(256) void knn_select_kernel(
    const float4* __restrict__ pts4, const ushort* __restrict__ buf,
    const ushort* __restrict__ cnt, int* __restrict__ iout)
{
    __shared__ ull sm3[4][4][16][KK];   // 32 KB

    const int t = threadIdx.x;
    const int wv = t >> 6, lane = t & 63;
    const int qq = lane & 15, hh = lane >> 4;
    const int q  = (blockIdx.x * 4 + wv) * 16 + qq;    // global query 0..16383
    const int b  = q >> 13;

    const float4 qp = pts4[q];
    ull list[KK];
#pragma unroll
    for (int i = 0; i < KK; ++i) list[i] = KINF;

#pragma unroll
    for (int ss = 0; ss < 4; ++ss) {
        const int s = hh * 4 + ss;
        const int cell = (q << 4) + s;
        const int n = cnt[cell];
        const ushort* bp = buf + (size_t)cell * CAP;
        for (int i = 0; i < n; ++i) {
            int id = bp[i];
            float4 c = pts4[b * NN + id];
            float dot = fmaf(qp.z, c.z, fmaf(qp.y, c.y, __fmul_rn(qp.x, c.x)));
            float d = __fadd_rn(__fsub_rn(qp.w, __fmul_rn(2.0f, dot)), c.w);
            unsigned ud = __float_as_uint(d);
            ud ^= ((unsigned)((int)ud >> 31)) | 0x80000000u;
            ull k = ((ull)ud << 32) | (unsigned)id;
#pragma unroll
            for (int i2 = KK - 1; i2 > 0; --i2) {
                bool c1 = k < list[i2];
                bool c2 = k < list[i2 - 1];
                ull nd = c2 ? list[i2 - 1] : k;
                list[i2] = c1 ? nd : list[i2];
            }
            list[0] = (k < list[0]) ? k : list[0];
        }
    }

#pragma unroll
    for (int k = 0; k < KK; ++k) sm3[wv][hh][qq][k] = list[k];

    if (hh == 0) {
        ull h[4]; int kc[4];
#pragma unroll
        for (int s = 0; s < 4; ++s) { h[s] = sm3[wv][s][qq][0]; kc[s] = 0; }
        int* op = iout + (size_t)q * KK;
        for (int o = 0; o < KK; ++o) {
            ull best = h[0]; int bs = 0;
#pragma unroll
            for (int s = 1; s < 4; ++s) { if (h[s] < best) { best = h[s]; bs = s; } }
            op[o] = (int)(unsigned)(best & 0xFFFFFFFFULL);
#pragma unroll
            for (int s = 0; s < 4; ++s) {
                if (s == bs) {
                    kc[s]++;
                    h[s] = (kc[s] < KK) ? sm3[wv][s][qq][kc[s]] : KINF;
                }
            }
        }
    }
}

// ---------------------------------------------------------------- f1
__global__ __launch_bounds__(128) void f1_kernel(
    const float* __restrict__ x,
    const float* __restrict__ w1, const float* __restrict__ b1,
    const float* __restrict__ w2, const float* __restrict__ b2,
    float* __restrict__ f1)
{
    int P = blockIdx.x * 128 + threadIdx.x;
    if (P >= BB * NN) return;
    int b = P >> 13, n = P & (NN - 1);
    float x0 = x[(b * 3 + 0) * NN + n];
    float x1 = x[(b * 3 + 1) * NN + n];
    float x2 = x[(b * 3 + 2) * NN + n];
    float h[32];
#pragma unroll
    for (int o = 0; o < 32; ++o) {
        float v = fmaf(w1[o * 3 + 2], x2, fmaf(w1[o * 3 + 1], x1, fmaf(w1[o * 3 + 0], x0, b1[o])));
        h[o] = fmaxf(v, 0.f);
    }
    float4* out4 = (float4*)(f1 + (size_t)P * 64);
#pragma unroll
    for (int o4 = 0; o4 < 16; ++o4) {
        float vv[4];
#pragma unroll
        for (int u = 0; u < 4; ++u) {
            int o = o4 * 4 + u;
            float v = b2[o];
#pragma unroll
            for (int k = 0; k < 32; ++k) v = fmaf(w2[o * 32 + k], h[k], v);
            vv[u] = fmaxf(v, 0.f);
        }
        out4[o4] = make_float4(vv[0], vv[1], vv[2], vv[3]);
    }
}

// ---------------------------------------------------------------- attention (bf16 MFMA) — verified round 4
__global__ __launch_bounds__(256, 2) void attn_kernel(
    const float* __restrict__ f1, const int* __restrict__ idx,
    const float* __restrict__ aw1, const float* __restrict__ ab1,
    const float* __restrict__ aw2, const float* __restrict__ ab2,
    float* __restrict__ fagg)
{
    __shared__ __align__(16) ushort fkb[4][16][72];    // stride 144 B
    __shared__ __align__(16) ushort hb[4][16][136];    // stride 272 B

    const int t = threadIdx.x;
    const int wv = t >> 6, lane = t & 63;
    const int l15 = lane & 15, qd = lane >> 4;

    short8 w1f[8][2];
#pragma unroll
    for (int tile = 0; tile < 8; ++tile)
#pragma unroll
        for (int ks = 0; ks < 2; ++ks) {
            const float4* p = (const float4*)(aw1 + ((tile * 16 + l15) * 64 + ks * 32 + qd * 8));
            float4 A = p[0], B = p[1];
            short8 f;
            f[0] = f2bf(A.x); f[1] = f2bf(A.y); f[2] = f2bf(A.z); f[3] = f2bf(A.w);
            f[4] = f2bf(B.x); f[5] = f2bf(B.y); f[6] = f2bf(B.z); f[7] = f2bf(B.w);
            w1f[tile][ks] = f;
        }
    short8 w2f[4][4];
#pragma unroll
    for (int tile = 0; tile < 4; ++tile)
#pragma unroll
        for (int ks = 0; ks < 4; ++ks) {
            const float4* p = (const float4*)(aw2 + ((tile * 16 + l15) * 128 + ks * 32 + qd * 8));
            float4 A = p[0], B = p[1];
            short8 f;
            f[0] = f2bf(A.x); f[1] = f2bf(A.y); f[2] = f2bf(A.z); f[3] = f2bf(A.w);
            f[4] = f2bf(B.x); f[5] = f2bf(B.y); f[6] = f2bf(B.z); f[7] = f2bf(B.w);
            w2f[tile][ks] = f;
        }

    const int W = blockIdx.x * 4 + wv;
    for (int g = 0; g < 8; ++g) {
        const int P = W * 8 + g;
        const int b = P >> 13;

        float fc = f1[(size_t)P * 64 + lane];
        float fn[15];
#pragma unroll
        for (int j = 0; j < 15; ++j) {
            int nb = idx[(size_t)P * KK + 1 + j];
            fn[j] = f1[((size_t)b * NN + nb) * 64 + lane];
        }
#pragma unroll
        for (int j = 0; j < 15; ++j) fkb[wv][j][lane] = f2bf(fn[j] - fc);
        fkb[wv][15][lane] = 0;

        short8 a0 = *(const short8*)&fkb[wv][l15][qd * 8];
        short8 a1 = *(const short8*)&fkb[wv][l15][32 + qd * 8];

#pragma unroll
        for (int tile = 0; tile < 8; ++tile) {
            float bv = ab1[tile * 16 + l15];
            f32x4 acc = { bv, bv, bv, bv };
            acc = __builtin_amdgcn_mfma_f32_16x16x32_bf16(a0, w1f[tile][0], acc, 0, 0, 0);
            acc = __builtin_amdgcn_mfma_f32_16x16x32_bf16(a1, w1f[tile][1], acc, 0, 0, 0);
#pragma unroll
            for (int reg = 0; reg < 4; ++reg)
                hb[wv][qd * 4 + reg][tile * 16 + l15] = f2bf(fmaxf(acc[reg], 0.f));
        }

        short8 a2[4];
#pragma unroll
        for (int ks = 0; ks < 4; ++ks)
            a2[ks] = *(const short8*)&hb[wv][l15][ks * 32 + qd * 8];

        f32x4 L[4];
#pragma unroll
        for (int tile = 0; tile < 4; ++tile) {
            float bv = ab2[tile * 16 + l15];
            f32x4 acc = { bv, bv, bv, bv };
#pragma unroll
            for (int ks = 0; ks < 4; ++ks)
                acc = __builtin_amdgcn_mfma_f32_16x16x32_bf16(a2[ks], w2f[tile][ks], acc, 0, 0, 0);
            L[tile] = acc;
        }

        float fa[4];
#pragma unroll
        for (int tile = 0; tile < 4; ++tile) {
            float m1 = -3.0e38f;
#pragma unroll
            for (int reg = 0; reg < 4; ++reg)
                if (qd * 4 + reg < 15) m1 = fmaxf(m1, L[tile][reg]);
            m1 = fmaxf(m1, __shfl_xor(m1, 16));
            m1 = fmaxf(m1, __shfl_xor(m1, 32));
            float e[4], ssum = 0.f;
#pragma unroll
            for (int reg = 0; reg < 4; ++reg) {
                bool valid = (qd * 4 + reg < 15);
                e[reg] = valid ? __expf(L[tile][reg] - m1) : 0.f;
                ssum += e[reg];
            }
            ssum += __shfl_xor(ssum, 16);
            ssum += __shfl_xor(ssum, 32);
            float part = 0.f;
#pragma unroll
            for (int reg = 0; reg < 4; ++reg) {
                float fkv = bf2f(fkb[wv][qd * 4 + reg][tile * 16 + l15]);
                part = fmaf(e[reg], fkv, part);
            }
            part += __shfl_xor(part, 16);
            part += __shfl_xor(part, 32);
            fa[tile] = part / ssum;
        }
        if (qd == 0) {
#pragma unroll
            for (int tile = 0; tile < 4; ++tile)
                fagg[(size_t)P * 64 + tile * 16 + l15] = fa[tile];
        }
    }
}

// ---------------------------------------------------------------- cov + mlp2
__global__ __launch_bounds__(128) void cov_kernel(
    const float4* __restrict__ pts4, const int* __restrict__ idx,
    const float* __restrict__ w, const float* __restrict__ bb,
    float* __restrict__ fcov)
{
    int P = blockIdx.x * 128 + threadIdx.x;
    if (P >= BB * NN) return;
    int b = P >> 13;
    const int4* ip4 = (const int4*)(idx + (size_t)P * KK);
    int ids[KK];
#pragma unroll
    for (int g = 0; g < 4; ++g) {
        int4 v = ip4[g];
        ids[g * 4 + 0] = v.x; ids[g * 4 + 1] = v.y;
        ids[g * 4 + 2] = v.z; ids[g * 4 + 3] = v.w;
    }
    float px[KK], py[KK], pz[KK];
#pragma unroll
    for (int k = 0; k < KK; ++k) {
        float4 c = pts4[b * NN + ids[k]];
        px[k] = c.x; py[k] = c.y; pz[k] = c.z;
    }
    float mx = 0.f, my = 0.f, mz = 0.f;
#pragma unroll
    for (int k = 0; k < KK; ++k) { mx += px[k]; my += py[k]; mz += pz[k]; }
    mx *= (1.f / 16.f); my *= (1.f / 16.f); mz *= (1.f / 16.f);
    float c00 = 0, c01 = 0, c02 = 0, c11 = 0, c12 = 0, c22 = 0;
#pragma unroll
    for (int k = 0; k < KK; ++k) {
        float dx = px[k] - mx, dy = py[k] - my, dz = pz[k] - mz;
        c00 = fmaf(dx, dx, c00); c01 = fmaf(dx, dy, c01); c02 = fmaf(dx, dz, c02);
        c11 = fmaf(dy, dy, c11); c12 = fmaf(dy, dz, c12); c22 = fmaf(dz, dz, c22);
    }
    const float inv = 1.f / 16.f;
    float cf[9] = { c00 * inv, c01 * inv, c02 * inv,
                    c01 * inv, c11 * inv, c12 * inv,
                    c02 * inv, c12 * inv, c22 * inv };
    float* out = fcov + (size_t)P * 32;
#pragma unroll
    for (int o = 0; o < 32; ++o) {
        float v = bb[o];
#pragma unroll
        for (int m = 0; m < 9; ++m) v = fmaf(w[o * 9 + m], cf[m], v);
        out[o] = fmaxf(v, 0.f);
    }
}

// ---------------------------------------------------------------- mlp3 + output (bf16 MFMA, attn-style)
// wave = 16-point tile; layer1: H(16x128) = f(16x96) x W1^T (3 K-steps),
// relu; layer2: D(16x12) = H x W2^T (W2 rows = B n-index, 12 valid of 16).
// f staged to LDS in A-layout (pad 104/136 shorts -> full bank coverage).
__global__ __launch_bounds__(256) void mlp3_kernel(
    const float* __restrict__ fagg, const float* __restrict__ fcov,
    const float* __restrict__ w1, const float* __restrict__ b1,
    const float* __restrict__ w2, const float* __restrict__ b2,
    const float* __restrict__ x, float* __restrict__ out)
{
    __shared__ __align__(16) ushort fb[4][16][104];    // 13.3 KB
    __shared__ __align__(16) ushort hb[4][16][136];    // 17.4 KB

    const int t = threadIdx.x;
    const int wv = t >> 6, lane = t & 63;
    const int l15 = lane & 15, qd = lane >> 4;

    // ---- preload weight B-frags (bf16)
    short8 w1f[8][3];
#pragma unroll
    for (int tile = 0; tile < 8; ++tile)
#pragma unroll
        for (int ks = 0; ks < 3; ++ks) {
            const float* p = w1 + ((size_t)(tile * 16 + l15) * 96 + ks * 32 + qd * 8);
            float4 A = *(const float4*)p, B = *(const float4*)(p + 4);
            short8 f;
            f[0] = f2bf(A.x); f[1] = f2bf(A.y); f[2] = f2bf(A.z); f[3] = f2bf(A.w);
            f[4] = f2bf(B.x); f[5] = f2bf(B.y); f[6] = f2bf(B.z); f[7] = f2bf(B.w);
            w1f[tile][ks] = f;
        }
    short8 w2f[4];
#pragma unroll
    for (int ks = 0; ks < 4; ++ks) {
        short8 f = {};
        if (l15 < 12) {
            const float* p = w2 + ((size_t)l15 * 128 + ks * 32 + qd * 8);
            float4 A = *(const float4*)p, B = *(const float4*)(p + 4);
            f[0] = f2bf(A.x); f[1] = f2bf(A.y); f[2] = f2bf(A.z); f[3] = f2bf(A.w);
            f[4] = f2bf(B.x); f[5] = f2bf(B.y); f[6] = f2bf(B.z); f[7] = f2bf(B.w);
        }
        w2f[ks] = f;
    }

    const int T = blockIdx.x * 4 + wv;    // tile 0..1023

    // ---- stage f = [fagg | fcov] as bf16 in A-layout
    {
        const int pt = lane >> 2, c4 = lane & 3;
        const float* fap = fagg + ((size_t)(T * 16 + pt) * 64 + c4 * 16);
#pragma unroll
        for (int i = 0; i < 4; ++i) {
            float4 v = *(const float4*)(fap + i * 4);
            ushort4 s = { f2bf(v.x), f2bf(v.y), f2bf(v.z), f2bf(v.w) };
            *(ushort4*)&fb[wv][pt][c4 * 16 + i * 4] = s;
        }
        const float* fcp = fcov + ((size_t)(T * 16 + pt) * 32 + c4 * 8);
#pragma unroll
        for (int i = 0; i < 2; ++i) {
            float4 v = *(const float4*)(fcp + i * 4);
            ushort4 s = { f2bf(v.x), f2bf(v.y), f2bf(v.z), f2bf(v.w) };
            *(ushort4*)&fb[wv][pt][64 + c4 * 8 + i * 4] = s;
        }
    }

    // ---- A-frags layer 1
    short8 a[3];
#pragma unroll
    for (int ks = 0; ks < 3; ++ks)
        a[ks] = *(const short8*)&fb[wv][l15][ks * 32 + qd * 8];

    // ---- layer 1 -> relu -> LDS (C->A transit)
#pragma unroll
    for (int tile = 0; tile < 8; ++tile) {
        float bv = b1[tile * 16 + l15];
        f32x4 acc = { bv, bv, bv, bv };
#pragma unroll
        for (int ks = 0; ks < 3; ++ks)
            acc = __builtin_amdgcn_mfma_f32_16x16x32_bf16(a[ks], w1f[tile][ks], acc, 0, 0, 0);
#pragma unroll
        for (int reg = 0; reg < 4; ++reg)
            hb[wv][qd * 4 + reg][tile * 16 + l15] = f2bf(fmaxf(acc[reg], 0.f));
    }

    // ---- layer 2
    short8 a2[4];
#pragma unroll
    for (int ks = 0; ks < 4; ++ks)
        a2[ks] = *(const short8*)&hb[wv][l15][ks * 32 + qd * 8];

    float bv2 = (l15 < 12) ? b2[l15] : 0.f;
    f32x4 acc = { bv2, bv2, bv2, bv2 };
#pragma unroll
    for (int ks = 0; ks < 4; ++ks)
        acc = __builtin_amdgcn_mfma_f32_16x16x32_bf16(a2[ks], w2f[ks], acc, 0, 0, 0);

    // ---- epilogue: out[((b*3+c)*4+rr)*N + n] = x + 0.15*g
    if (l15 < 12) {
        const int c = l15 >> 2, rr = l15 & 3;
#pragma unroll
        for (int reg = 0; reg < 4; ++reg) {
            int P = T * 16 + qd * 4 + reg;
            int b = P >> 13, n = P & (NN - 1);
            float xv = x[((size_t)b * 3 + c) * NN + n];
            out[(((size_t)b * 3 + c) * 4 + rr) * NN + n] = xv + 0.15f * acc[reg];
        }
    }
}

// ---------------------------------------------------------------- launch
extern "C" void kernel_launch(void* const* d_in, const int* in_sizes, int n_in,
                              void* d_out, int out_size, void* d_ws, size_t ws_size,
                              hipStream_t stream)
{
    (void)in_sizes; (void)n_in; (void)out_size; (void)ws_size;
    const float* x    = (const float*)d_in[0];
    const float* m1w1 = (const float*)d_in[1];
    const float* m1b1 = (const float*)d_in[2];
    const float* m1w2 = (const float*)d_in[3];
    const float* m1b2 = (const float*)d_in[4];
    const float* m2w1 = (const float*)d_in[5];
    const float* m2b1 = (const float*)d_in[6];
    const float* m3w1 = (const float*)d_in[7];
    const float* m3b1 = (const float*)d_in[8];
    const float* m3w2 = (const float*)d_in[9];
    const float* m3b2 = (const float*)d_in[10];
    const float* aw1  = (const float*)d_in[11];
    const float* ab1  = (const float*)d_in[12];
    const float* aw2  = (const float*)d_in[13];
    const float* ab2  = (const float*)d_in[14];
    float* out = (float*)d_out;

    char* ws = (char*)d_ws;
    float4* pts4 = (float4*)(ws + 0);             //   262144 B
    float*  thrb = (float*)(ws + 262144);         //    65536 B
    int*    idxb = (int*)  (ws + 327680);         //  1048576 B
    ushort* cntb = (ushort*)(ws + 1376256);       //   524288 B
    ushort* bufb = (ushort*)(ws + 1900544);       //  8388608 B
    float*  f1   = (float*)(ws + 10289152);       //  4194304 B
    float*  fagg = (float*)(ws + 14483456);       //  4194304 B
    float*  fcov = (float*)(ws + 18677760);       //  2097152 B

    prep_kernel<<<64, 256, 0, stream>>>(x, pts4);
    knn_prefix_kernel<<<dim3(NN / QPB, BB), 512, 0, stream>>>(pts4, thrb);
    knn_scan_kernel<<<dim3(NN / QPB, BB, 2), 512, 0, stream>>>(pts4, thrb, bufb, cntb);
    knn_select_kernel<<<256, 256, 0, stream>>>(pts4, bufb, cntb, idxb);
    f1_kernel<<<128, 128, 0, stream>>>(x, m1w1, m1b1, m1w2, m1b2, f1);
    attn_kernel<<<512, 256, 0, stream>>>(f1, idxb, aw1, ab1, aw2, ab2, fagg);
    cov_kernel<<<128, 128, 0, stream>>>(pts4, idxb, m2w1, m2b1, fcov);
    mlp3_kernel<<<256, 256, 0, stream>>>(fagg, fcov, m3w1, m3b1, m3w2, m3b2, x, out);
}